// Round 6
// baseline (822.754 us; speedup 1.0000x reference)
//
#include <hip/hip_runtime.h>
#include <hip/hip_bf16.h>
#include <math.h>

#define DI __device__ __forceinline__

typedef unsigned short u16;
typedef unsigned int   u32;
typedef unsigned long long u64;
typedef __attribute__((ext_vector_type(8))) short short8;   // 8 bf16 (4 VGPRs) MFMA A/B frag
typedef __attribute__((ext_vector_type(4))) float f32x4;    // MFMA C/D frag

constexpr int CB = 512;    // channels
constexpr int LL = 4096;   // length
constexpr int NG = 32;     // groups

DI float bf2f(u16 u) { u32 v = ((u32)u) << 16; float f; __builtin_memcpy(&f, &v, 4); return f; }
DI u16 f2bf(float f) {
  u32 u; __builtin_memcpy(&u, &f, 4);
  u += 0x7fffu + ((u >> 16) & 1u);   // RNE
  return (u16)(u >> 16);
}

DI void gload16(const void* g, void* l) {
  __builtin_amdgcn_global_load_lds((const __attribute__((address_space(1))) u32*)g,
                                   (__attribute__((address_space(3))) u32*)l, 16, 0, 0);
}

// ---------------------------------------------------------------------------
// K0: weights -> bf16 (wqkv fused [1536][512], wo [512][512]); fused bias.
// ---------------------------------------------------------------------------
__global__ __launch_bounds__(256) void conv_w(
    const float* __restrict__ wq, const float* __restrict__ wk,
    const float* __restrict__ wv, const float* __restrict__ wo,
    const float* __restrict__ bq, const float* __restrict__ bk,
    const float* __restrict__ bv,
    u16* __restrict__ wqkv, u16* __restrict__ wob, float* __restrict__ bqkv) {
  if (blockIdx.x < 1024) {
    int i = blockIdx.x * 256 + threadIdx.x;
    wqkv[i]          = f2bf(wq[i]);
    wqkv[262144 + i] = f2bf(wk[i]);
    wqkv[524288 + i] = f2bf(wv[i]);
    wob[i]           = f2bf(wo[i]);
  } else {
    for (int j = 0; j < 6; ++j) {
      int idx = j * 256 + threadIdx.x;
      float b = (idx < 512) ? bq[idx] : (idx < 1024) ? bk[idx - 512] : bv[idx - 1024];
      bqkv[idx] = b;
    }
  }
}

// ---------------------------------------------------------------------------
// K1: GroupNorm stats. One block per (b,g).
// ---------------------------------------------------------------------------
__global__ __launch_bounds__(256) void gn_stats(const float* __restrict__ x,
                                                float* __restrict__ stats) {
  const float4* base = (const float4*)(x + (long)blockIdx.x * (16 * LL));
  float s = 0.f, ss = 0.f;
  for (int i = threadIdx.x; i < 16 * LL / 4; i += 256) {
    float4 v = base[i];
    s  += v.x + v.y + v.z + v.w;
    ss += v.x * v.x + v.y * v.y + v.z * v.z + v.w * v.w;
  }
#pragma unroll
  for (int o = 32; o; o >>= 1) { s += __shfl_xor(s, o); ss += __shfl_xor(ss, o); }
  __shared__ float red[8];
  int wv = threadIdx.x >> 6, ln = threadIdx.x & 63;
  if (ln == 0) { red[wv * 2] = s; red[wv * 2 + 1] = ss; }
  __syncthreads();
  if (threadIdx.x == 0) {
    float S = red[0] + red[2] + red[4] + red[6];
    float SS = red[1] + red[3] + red[5] + red[7];
    float mu = S * (1.f / 65536.f);
    float var = SS * (1.f / 65536.f) - mu * mu;
    stats[blockIdx.x * 2]     = mu;
    stats[blockIdx.x * 2 + 1] = rsqrtf(var + 1e-6f);
  }
}

// ---------------------------------------------------------------------------
// K2: GroupNorm apply + transpose: hT[b][l][c] = bf16(gn(x[b][c][l]))
// ---------------------------------------------------------------------------
__global__ __launch_bounds__(256) void gn_apply(
    const float* __restrict__ x, const float* __restrict__ gw,
    const float* __restrict__ gb, const float* __restrict__ stats,
    u16* __restrict__ hT) {
  __shared__ u16 t[64][66];
  const int b = blockIdx.z, c0 = blockIdx.y * 64, l0 = blockIdx.x * 64;
  const int ln = threadIdx.x & 63, sub = threadIdx.x >> 6;
  for (int cr = sub; cr < 64; cr += 4) {
    int c = c0 + cr;
    float v  = x[(long)b * CB * LL + (long)c * LL + l0 + ln];
    float mu = stats[(b * NG + (c >> 4)) * 2];
    float rs = stats[(b * NG + (c >> 4)) * 2 + 1];
    t[cr][ln] = f2bf((v - mu) * rs * gw[c] + gb[c]);
  }
  __syncthreads();
  for (int lr = sub; lr < 64; lr += 4)
    hT[(long)b * LL * CB + (long)(l0 + lr) * CB + c0 + ln] = t[ln][lr];
}

// ---------------------------------------------------------------------------
// Shared GEMM skeleton: D[M][N] = A[M][K] * Bt[N][K]^T  (both k-contiguous)
// BK=64, WR x WC waves (wave tile (BM/WR)x(BN/WC)), 16x16x32 bf16 MFMA,
// LDS XOR-swizzled staging (linear global_load_lds dest + pre-swizzled
// global source — rule #21).
// EPI: 0=QKV (q,k,v ALL stored transposed [l][c]; +bias)
//      2=bf16 row-major tile store via LDS repack
//      3=fused attn-out (fp32: acc/lsum[col] + bias + xres)
//      5=expS (no-max softmax numerator, bf16) + atomic row-sums -> lsum
// SWZ: bijective XCD-chunked blockIdx swizzle (requires nwg%8==0).
// MF:  m-fastest raster (blockIdx.x = m-tile) for B-panel L3 reuse.
// ---------------------------------------------------------------------------
template <int BM, int BN, int EPI, bool SWZ, bool MF, int WR, int WC>
__global__ __launch_bounds__(WR * WC * 64) void gemm_bt(
    const u16* __restrict__ A, int lda, long asb,
    const u16* __restrict__ Bt, int ldb, long bsb,
    int K, const float* __restrict__ bias, float scale,
    u16* __restrict__ o0, u16* __restrict__ o1, u16* __restrict__ o2,
    float* __restrict__ of, const float* __restrict__ xres,
    float* __restrict__ lsum, long osb, int ldo) {
  constexpr int NT = WR * WC * 64;
  constexpr int FM = BM / WR / 16, FN = BN / WC / 16;
  static_assert((BM * 8) % NT == 0 && (BN * 8) % NT == 0, "staging div");
  __shared__ u16 smem[(BM + BN) * 64];
  u16* lA = smem;
  u16* lB = smem + BM * 64;

  int bx, by;
  if constexpr (MF) {
    by = blockIdx.x; bx = blockIdx.y;
  } else {
    bx = blockIdx.x; by = blockIdx.y;
    if constexpr (SWZ) {
      const int nwg = gridDim.x * gridDim.y;
      const int id = by * gridDim.x + bx;
      const int id2 = (id & 7) * (nwg >> 3) + (id >> 3);
      bx = id2 % gridDim.x;
      by = id2 / gridDim.x;
    }
  }

  const int tid = threadIdx.x;
  const int lane = tid & 63;
  const int wv = tid >> 6;
  const int wr = wv / WC, wc = wv % WC;
  const int fr = lane & 15, fq = lane >> 4;
  const int bz = blockIdx.z;

  const u16* Ab = A + (long)bz * asb + (long)(by * BM) * lda;
  const u16* Bb = Bt + (long)bz * bsb + (long)(bx * BN) * ldb;

  f32x4 acc[FM][FN];
#pragma unroll
  for (int m = 0; m < FM; ++m)
#pragma unroll
    for (int n = 0; n < FN; ++n) acc[m][n] = (f32x4)(0.f);

  for (int k0 = 0; k0 < K; k0 += 64) {
#pragma unroll
    for (int p = 0; p < BM * 8 / NT; ++p) {
      int t = p * NT + tid;
      int row = t >> 3;
      int cbl = ((t & 7) << 4) ^ ((row & 7) << 4);     // inverse-swizzled source col (bytes)
      gload16(Ab + (long)row * lda + k0 + (cbl >> 1), &lA[t * 8]);
    }
#pragma unroll
    for (int p = 0; p < BN * 8 / NT; ++p) {
      int t = p * NT + tid;
      int row = t >> 3;
      int cbl = ((t & 7) << 4) ^ ((row & 7) << 4);
      gload16(Bb + (long)row * ldb + k0 + (cbl >> 1), &lB[t * 8]);
    }
    __syncthreads();
#pragma unroll
    for (int ks = 0; ks < 2; ++ks) {
      short8 af[FM], bfr[FN];
#pragma unroll
      for (int m = 0; m < FM; ++m) {
        int row = wr * (BM / WR) + m * 16 + fr;
        int cb = (ks * 64 + fq * 16) ^ ((row & 7) << 4);
        af[m] = *(const short8*)((const char*)lA + row * 128 + cb);
      }
#pragma unroll
      for (int n = 0; n < FN; ++n) {
        int row = wc * (BN / WC) + n * 16 + fr;
        int cb = (ks * 64 + fq * 16) ^ ((row & 7) << 4);
        bfr[n] = *(const short8*)((const char*)lB + row * 128 + cb);
      }
#pragma unroll
      for (int m = 0; m < FM; ++m)
#pragma unroll
        for (int n = 0; n < FN; ++n)
          acc[m][n] = __builtin_amdgcn_mfma_f32_16x16x32_bf16(af[m], bfr[n], acc[m][n], 0, 0, 0);
    }
    __syncthreads();
  }

  const int ml0 = wr * (BM / WR);
  const int nl0 = wc * (BN / WC);

  if constexpr (EPI == 3) {
    // fused attention-out: fp32 = acc / lsum[col] + bias[m] + xres
    const int mg0 = by * BM + ml0;
    const int ng0 = bx * BN + nl0;
#pragma unroll
    for (int n = 0; n < FN; ++n) {
      const int ng = ng0 + n * 16 + fr;
      const float il = 1.0f / lsum[(long)bz * LL + ng];
#pragma unroll
      for (int m = 0; m < FM; ++m)
#pragma unroll
        for (int r = 0; r < 4; ++r) {
          const int mg = mg0 + m * 16 + fq * 4 + r;
          const long off = (long)bz * osb + (long)mg * ldo + ng;
          of[off] = acc[m][n][r] * il + bias[mg] + xres[off];
        }
    }
  } else if constexpr (EPI == 0) {
    // QKV: all three outputs stored transposed [l][c].  by in [0,12): mat=by>>2
    const int mat = by >> 2;
    u16* pl = (mat == 0) ? o0 : (mat == 1) ? o1 : o2;
#pragma unroll
    for (int m = 0; m < FM; ++m)
#pragma unroll
      for (int n = 0; n < FN; ++n) {
        const int nl = nl0 + n * 16 + fr;
#pragma unroll
        for (int r = 0; r < 4; ++r) {
          const int ml = ml0 + m * 16 + fq * 4 + r;
          smem[nl * BM + (ml ^ ((nl & 7) << 3))] =
              f2bf(acc[m][n][r] + bias[by * BM + ml]);
        }
      }
    __syncthreads();
    u16* dst0 = pl + (long)bz * ((long)LL * CB) +
                (long)(bx * BN) * CB + ((by * BM) & 511);
    for (int i = tid * 8; i < BM * BN; i += NT * 8) {
      const int rr = i / BM, cc = i % BM;
      short8 val = *(const short8*)&smem[rr * BM + (cc ^ ((rr & 7) << 3))];
      *(short8*)(dst0 + (long)rr * CB + cc) = val;
    }
  } else if constexpr (EPI == 5) {
    // expS + row-sum atomics (no-max softmax: shift-invariant, exp <= ~e^6)
    float rsum[FM][4];
#pragma unroll
    for (int m = 0; m < FM; ++m)
#pragma unroll
      for (int r = 0; r < 4; ++r) rsum[m][r] = 0.f;
#pragma unroll
    for (int m = 0; m < FM; ++m)
#pragma unroll
      for (int n = 0; n < FN; ++n) {
        const int nl = nl0 + n * 16 + fr;
#pragma unroll
        for (int r = 0; r < 4; ++r) {
          const int ml = ml0 + m * 16 + fq * 4 + r;
          float p = exp2f(acc[m][n][r] * scale);
          rsum[m][r] += p;
          smem[ml * BN + (nl ^ ((ml & 7) << 3))] = f2bf(p);
        }
      }
#pragma unroll
    for (int m = 0; m < FM; ++m)
#pragma unroll
      for (int r = 0; r < 4; ++r) {
        float v = rsum[m][r];
        v += __shfl_xor(v, 1); v += __shfl_xor(v, 2);
        v += __shfl_xor(v, 4); v += __shfl_xor(v, 8);
        if (fr == 0)
          atomicAdd(&lsum[(long)bz * LL + by * BM + ml0 + m * 16 + fq * 4 + r], v);
      }
    __syncthreads();
    u16* dst0 = o0 + (long)bz * osb + (long)(by * BM) * ldo + bx * BN;
    for (int i = tid * 8; i < BM * BN; i += NT * 8) {
      const int rr = i / BN, cc = i % BN;
      short8 val = *(const short8*)&smem[rr * BN + (cc ^ ((rr & 7) << 3))];
      *(short8*)(dst0 + (long)rr * ldo + cc) = val;
    }
  } else {
    // EPI 2: row-major [m][n] bf16 tile
#pragma unroll
    for (int m = 0; m < FM; ++m)
#pragma unroll
      for (int n = 0; n < FN; ++n) {
        const int nl = nl0 + n * 16 + fr;
#pragma unroll
        for (int r = 0; r < 4; ++r) {
          const int ml = ml0 + m * 16 + fq * 4 + r;
          smem[ml * BN + (nl ^ ((ml & 7) << 3))] = f2bf(acc[m][n][r] * scale);
        }
      }
    __syncthreads();
    u16* dst0 = o0 + (long)bz * osb + (long)(by * BM) * ldo + bx * BN;
    for (int i = tid * 8; i < BM * BN; i += NT * 8) {
      const int rr = i / BN, cc = i % BN;
      short8 val = *(const short8*)&smem[rr * BN + (cc ^ ((rr & 7) << 3))];
      *(short8*)(dst0 + (long)rr * ldo + cc) = val;
    }
  }
}

// ---------------------------------------------------------------------------
extern "C" void kernel_launch(void* const* d_in, const int* in_sizes, int n_in,
                              void* d_out, int out_size, void* d_ws, size_t ws_size,
                              hipStream_t stream) {
  const float* x   = (const float*)d_in[0];
  const float* gnw = (const float*)d_in[1];
  const float* gnb = (const float*)d_in[2];
  const float* wq  = (const float*)d_in[3];
  const float* bq  = (const float*)d_in[4];
  const float* wk  = (const float*)d_in[5];
  const float* bk  = (const float*)d_in[6];
  const float* wv  = (const float*)d_in[7];
  const float* bv  = (const float*)d_in[8];
  const float* wo  = (const float*)d_in[9];
  const float* bo  = (const float*)d_in[10];
  float* out = (float*)d_out;

  char* ws = (char*)d_ws;
  const long NEL = (long)LL * CB;          // 2M elems = 4 MB bf16 per batch-plane
  const long SEL = (long)LL * LL;          // 16M elems = 32 MB bf16 per batch S
  float* stats = (float*)ws;                               // 8 KB
  float* bqkv  = (float*)(ws + 8192);                      // 6 KB
  u16* wqkv = (u16*)(ws + 16384);                          // 1.5 MB
  u16* wob  = (u16*)(ws + 16384 + 1572864);                // 0.5 MB
  u16* hT   = (u16*)(ws + (4l << 20));                     // 32 MB  [B][L][C]; = W after QKV
  u16* qT   = hT + 8 * NEL;                                // 32 MB  [B][L][C]
  u16* kT   = qT + 8 * NEL;                                // 32 MB  [B][L][C]
  u16* vT   = kT + 8 * NEL;                                // 32 MB  [B][L][C]
  u16* W    = hT;                                          // W[b][o][j], hT dead after QKV
  const size_t base = (4ul << 20) + 4ul * 8 * NEL * 2;     // 132 MB
  u16* Sbuf = (u16*)(ws + base);

  const int G = (ws_size >= base + 2ul * SEL * 2 + (1ul << 16)) ? 2 : 1;
  float* lsum = (float*)(ws + base + (size_t)G * SEL * 2); // G*16 KB

  conv_w<<<1025, 256, 0, stream>>>(wq, wk, wv, wo, bq, bk, bv, wqkv, wob, bqkv);
  gn_stats<<<256, 256, 0, stream>>>(x, stats);
  gn_apply<<<dim3(64, 8, 8), 256, 0, stream>>>(x, gnw, gnb, stats, hT);

  // fused QKV: A=wqkv [1536][512], Bt=hT[b] [4096][512]; q,k,v all -> [l][c]
  gemm_bt<128, 128, 0, false, false, 2, 2><<<dim3(32, 12, 8), 256, 0, stream>>>(
      wqkv, 512, 0, hT, 512, NEL, 512, bqkv, 1.f, qT, kT, vT,
      nullptr, nullptr, nullptr, 0, 0);

  // W[b] = wo * v[b]: A=wob [512][512], Bt=vT[b] [4096][512]; M=512 N=4096 K=512
  gemm_bt<128, 128, 2, false, false, 2, 2><<<dim3(32, 4, 8), 256, 0, stream>>>(
      wob, 512, 0, vT, 512, NEL, 512, nullptr, 1.f,
      W, nullptr, nullptr, nullptr, nullptr, nullptr, NEL, LL);

  // scale folded with log2(e): p = exp2(S * scal * log2e)
  const float cl = (1.0f / sqrtf(512.0f)) * 1.44269504f;
  for (int g0 = 0; g0 < 8; g0 += G) {
    hipMemsetAsync(lsum, 0, (size_t)G * LL * sizeof(float), stream);
    // expS[z] = exp2(cl * qT[g0+z] * kT[g0+z]^T), rowsums -> lsum : M=N=4096 K=512
    gemm_bt<128, 128, 5, true, false, 2, 2><<<dim3(32, 32, G), 256, 0, stream>>>(
        qT + (long)g0 * NEL, 512, NEL, kT + (long)g0 * NEL, 512, NEL, 512,
        nullptr, cl, Sbuf, nullptr, nullptr, nullptr, nullptr, lsum, SEL, LL);
    // out[g][o][i] = x + bo[o] + (sum_j W[g][o][j] expS[i][j]) / lsum[i]
    // M=512 N=4096 K=4096; m-fastest raster (8 consecutive blocks share P panel)
    gemm_bt<64, 128, 3, false, true, 2, 4><<<dim3(8, 32, G), 512, 0, stream>>>(
        W + (long)g0 * NEL, LL, NEL, Sbuf, LL, SEL, LL, bo, 1.f,
        nullptr, nullptr, nullptr, out + (long)g0 * NEL, x + (long)g0 * NEL,
        lsum, NEL, LL);
  }

  (void)in_sizes; (void)n_in; (void)out_size; (void)ws_size;
}

// Round 7
// 809.436 us; speedup vs baseline: 1.0165x; 1.0165x over previous
//
#include <hip/hip_runtime.h>
#include <hip/hip_bf16.h>
#include <math.h>

#define DI __device__ __forceinline__

typedef unsigned short u16;
typedef unsigned int   u32;
typedef unsigned long long u64;
typedef __attribute__((ext_vector_type(8))) short short8;   // 8 bf16 (4 VGPRs) MFMA A/B frag
typedef __attribute__((ext_vector_type(4))) float f32x4;    // MFMA C/D frag

constexpr int CB = 512;    // channels
constexpr int LL = 4096;   // length
constexpr int NG = 32;     // groups

DI float bf2f(u16 u) { u32 v = ((u32)u) << 16; float f; __builtin_memcpy(&f, &v, 4); return f; }
DI u16 f2bf(float f) {
  u32 u; __builtin_memcpy(&u, &f, 4);
  u += 0x7fffu + ((u >> 16) & 1u);   // RNE
  return (u16)(u >> 16);
}

DI void gload16(const void* g, void* l) {
  __builtin_amdgcn_global_load_lds((const __attribute__((address_space(1))) u32*)g,
                                   (__attribute__((address_space(3))) u32*)l, 16, 0, 0);
}

// ---------------------------------------------------------------------------
// K0: weights -> bf16 (wqkv fused [1536][512], wo [512][512]); fused bias.
// ---------------------------------------------------------------------------
__global__ __launch_bounds__(256) void conv_w(
    const float* __restrict__ wq, const float* __restrict__ wk,
    const float* __restrict__ wv, const float* __restrict__ wo,
    const float* __restrict__ bq, const float* __restrict__ bk,
    const float* __restrict__ bv,
    u16* __restrict__ wqkv, u16* __restrict__ wob, float* __restrict__ bqkv) {
  if (blockIdx.x < 1024) {
    int i = blockIdx.x * 256 + threadIdx.x;
    wqkv[i]          = f2bf(wq[i]);
    wqkv[262144 + i] = f2bf(wk[i]);
    wqkv[524288 + i] = f2bf(wv[i]);
    wob[i]           = f2bf(wo[i]);
  } else {
    for (int j = 0; j < 6; ++j) {
      int idx = j * 256 + threadIdx.x;
      float b = (idx < 512) ? bq[idx] : (idx < 1024) ? bk[idx - 512] : bv[idx - 1024];
      bqkv[idx] = b;
    }
  }
}

// ---------------------------------------------------------------------------
// K1: GroupNorm stats. One block per (b,g).
// ---------------------------------------------------------------------------
__global__ __launch_bounds__(256) void gn_stats(const float* __restrict__ x,
                                                float* __restrict__ stats) {
  const float4* base = (const float4*)(x + (long)blockIdx.x * (16 * LL));
  float s = 0.f, ss = 0.f;
  for (int i = threadIdx.x; i < 16 * LL / 4; i += 256) {
    float4 v = base[i];
    s  += v.x + v.y + v.z + v.w;
    ss += v.x * v.x + v.y * v.y + v.z * v.z + v.w * v.w;
  }
#pragma unroll
  for (int o = 32; o; o >>= 1) { s += __shfl_xor(s, o); ss += __shfl_xor(ss, o); }
  __shared__ float red[8];
  int wv = threadIdx.x >> 6, ln = threadIdx.x & 63;
  if (ln == 0) { red[wv * 2] = s; red[wv * 2 + 1] = ss; }
  __syncthreads();
  if (threadIdx.x == 0) {
    float S = red[0] + red[2] + red[4] + red[6];
    float SS = red[1] + red[3] + red[5] + red[7];
    float mu = S * (1.f / 65536.f);
    float var = SS * (1.f / 65536.f) - mu * mu;
    stats[blockIdx.x * 2]     = mu;
    stats[blockIdx.x * 2 + 1] = rsqrtf(var + 1e-6f);
  }
}

// ---------------------------------------------------------------------------
// K2: GroupNorm apply + transpose: hT[b][l][c] = bf16(gn(x[b][c][l]))
// ---------------------------------------------------------------------------
__global__ __launch_bounds__(256) void gn_apply(
    const float* __restrict__ x, const float* __restrict__ gw,
    const float* __restrict__ gb, const float* __restrict__ stats,
    u16* __restrict__ hT) {
  __shared__ u16 t[64][66];
  const int b = blockIdx.z, c0 = blockIdx.y * 64, l0 = blockIdx.x * 64;
  const int ln = threadIdx.x & 63, sub = threadIdx.x >> 6;
  for (int cr = sub; cr < 64; cr += 4) {
    int c = c0 + cr;
    float v  = x[(long)b * CB * LL + (long)c * LL + l0 + ln];
    float mu = stats[(b * NG + (c >> 4)) * 2];
    float rs = stats[(b * NG + (c >> 4)) * 2 + 1];
    t[cr][ln] = f2bf((v - mu) * rs * gw[c] + gb[c]);
  }
  __syncthreads();
  for (int lr = sub; lr < 64; lr += 4)
    hT[(long)b * LL * CB + (long)(l0 + lr) * CB + c0 + ln] = t[ln][lr];
}

// ---------------------------------------------------------------------------
// Shared GEMM skeleton: D[M][N] = A[M][K] * Bt[N][K]^T  (both k-contiguous)
// BK=64, WR x WC waves (wave tile (BM/WR)x(BN/WC)), 16x16x32 bf16 MFMA,
// LDS XOR-swizzled staging (linear global_load_lds dest + pre-swizzled
// global source — rule #21).
// EPI: 0=QKV (q,k,v ALL stored transposed [l][c]; +bias)
//      2=bf16 row-major tile store via LDS repack (*scale)
//      5=expS: p=exp2(acc*scale) bf16 store + NON-ATOMIC per-block row sums
//        -> of = spp[z][bx][4096]
//      6=split-K fout partial: bz=(chunk*nG+gl); store bf16(acc*rlsum[col])
//        -> plane o0 + (chunk*8+gl)*osb
// SWZ: bijective XCD-chunked blockIdx swizzle (requires nwg%8==0).
// MF:  m-fastest raster (blockIdx.x = m-tile) for B-panel L3 reuse.
// ---------------------------------------------------------------------------
template <int BM, int BN, int EPI, bool SWZ, bool MF, int WR, int WC>
__global__ __launch_bounds__(WR * WC * 64) void gemm_bt(
    const u16* __restrict__ A, int lda, long asb,
    const u16* __restrict__ Bt, int ldb, long bsb,
    int K, const float* __restrict__ bias, float scale,
    u16* __restrict__ o0, u16* __restrict__ o1, u16* __restrict__ o2,
    float* __restrict__ of, const float* __restrict__ xres,
    const float* __restrict__ lsum, long osb, int ldo, int nG) {
  constexpr int NT = WR * WC * 64;
  constexpr int FM = BM / WR / 16, FN = BN / WC / 16;
  static_assert((BM * 8) % NT == 0 && (BN * 8) % NT == 0, "staging div");
  __shared__ u16 smem[(BM + BN) * 64];
  u16* lA = smem;
  u16* lB = smem + BM * 64;

  int bx, by;
  if constexpr (MF) {
    by = blockIdx.x; bx = blockIdx.y;
  } else {
    bx = blockIdx.x; by = blockIdx.y;
    if constexpr (SWZ) {
      const int nwg = gridDim.x * gridDim.y;
      const int id = by * gridDim.x + bx;
      const int id2 = (id & 7) * (nwg >> 3) + (id >> 3);
      bx = id2 % gridDim.x;
      by = id2 / gridDim.x;
    }
  }

  const int tid = threadIdx.x;
  const int lane = tid & 63;
  const int wv = tid >> 6;
  const int wr = wv / WC, wc = wv % WC;
  const int fr = lane & 15, fq = lane >> 4;
  const int bz = blockIdx.z;
  const int glz = (EPI == 6) ? (bz % nG) : bz;      // batch within group
  const int kch = (EPI == 6) ? (bz / nG) : 0;       // split-K chunk

  const u16* Ab = A + (long)glz * asb + (long)(by * BM) * lda;
  const u16* Bb = Bt + (long)glz * bsb + (long)(bx * BN) * ldb;

  f32x4 acc[FM][FN];
#pragma unroll
  for (int m = 0; m < FM; ++m)
#pragma unroll
    for (int n = 0; n < FN; ++n) acc[m][n] = (f32x4)(0.f);

  const int kbeg = kch * K;
  for (int k0 = kbeg; k0 < kbeg + K; k0 += 64) {
#pragma unroll
    for (int p = 0; p < BM * 8 / NT; ++p) {
      int t = p * NT + tid;
      int row = t >> 3;
      int cbl = ((t & 7) << 4) ^ ((row & 7) << 4);     // inverse-swizzled source col (bytes)
      gload16(Ab + (long)row * lda + k0 + (cbl >> 1), &lA[t * 8]);
    }
#pragma unroll
    for (int p = 0; p < BN * 8 / NT; ++p) {
      int t = p * NT + tid;
      int row = t >> 3;
      int cbl = ((t & 7) << 4) ^ ((row & 7) << 4);
      gload16(Bb + (long)row * ldb + k0 + (cbl >> 1), &lB[t * 8]);
    }
    __syncthreads();
#pragma unroll
    for (int ks = 0; ks < 2; ++ks) {
      short8 af[FM], bfr[FN];
#pragma unroll
      for (int m = 0; m < FM; ++m) {
        int row = wr * (BM / WR) + m * 16 + fr;
        int cb = (ks * 64 + fq * 16) ^ ((row & 7) << 4);
        af[m] = *(const short8*)((const char*)lA + row * 128 + cb);
      }
#pragma unroll
      for (int n = 0; n < FN; ++n) {
        int row = wc * (BN / WC) + n * 16 + fr;
        int cb = (ks * 64 + fq * 16) ^ ((row & 7) << 4);
        bfr[n] = *(const short8*)((const char*)lB + row * 128 + cb);
      }
#pragma unroll
      for (int m = 0; m < FM; ++m)
#pragma unroll
        for (int n = 0; n < FN; ++n)
          acc[m][n] = __builtin_amdgcn_mfma_f32_16x16x32_bf16(af[m], bfr[n], acc[m][n], 0, 0, 0);
    }
    __syncthreads();
  }

  const int ml0 = wr * (BM / WR);
  const int nl0 = wc * (BN / WC);

  if constexpr (EPI == 0) {
    // QKV: all three outputs stored transposed [l][c].  by in [0,12): mat=by>>2
    const int mat = by >> 2;
    u16* pl = (mat == 0) ? o0 : (mat == 1) ? o1 : o2;
#pragma unroll
    for (int m = 0; m < FM; ++m)
#pragma unroll
      for (int n = 0; n < FN; ++n) {
        const int nl = nl0 + n * 16 + fr;
#pragma unroll
        for (int r = 0; r < 4; ++r) {
          const int ml = ml0 + m * 16 + fq * 4 + r;
          smem[nl * BM + (ml ^ ((nl & 7) << 3))] =
              f2bf(acc[m][n][r] + bias[by * BM + ml]);
        }
      }
    __syncthreads();
    u16* dst0 = pl + (long)bz * ((long)LL * CB) +
                (long)(bx * BN) * CB + ((by * BM) & 511);
    for (int i = tid * 8; i < BM * BN; i += NT * 8) {
      const int rr = i / BM, cc = i % BM;
      short8 val = *(const short8*)&smem[rr * BM + (cc ^ ((rr & 7) << 3))];
      *(short8*)(dst0 + (long)rr * CB + cc) = val;
    }
  } else if constexpr (EPI == 5) {
    // expS: p=exp2(acc*scale), bf16 tile + non-atomic per-block row sums
    __shared__ float sred2[2 * 128];          // [row within BM=128][wc]
    float rsum[FM][4];
#pragma unroll
    for (int m = 0; m < FM; ++m)
#pragma unroll
      for (int r = 0; r < 4; ++r) rsum[m][r] = 0.f;
#pragma unroll
    for (int m = 0; m < FM; ++m)
#pragma unroll
      for (int n = 0; n < FN; ++n) {
        const int nl = nl0 + n * 16 + fr;
#pragma unroll
        for (int r = 0; r < 4; ++r) {
          const int ml = ml0 + m * 16 + fq * 4 + r;
          float p = exp2f(acc[m][n][r] * scale);
          rsum[m][r] += p;
          smem[ml * BN + (nl ^ ((ml & 7) << 3))] = f2bf(p);
        }
      }
#pragma unroll
    for (int m = 0; m < FM; ++m)
#pragma unroll
      for (int r = 0; r < 4; ++r) {
        float v = rsum[m][r];
        v += __shfl_xor(v, 1); v += __shfl_xor(v, 2);
        v += __shfl_xor(v, 4); v += __shfl_xor(v, 8);
        if (fr == 0) sred2[(ml0 + m * 16 + fq * 4 + r) * 2 + wc] = v;
      }
    __syncthreads();
    if (tid < BM) {
      float s = sred2[tid * 2] + sred2[tid * 2 + 1];
      // spp layout [z][bx 32][row 4096] -> coalesced block write
      of[((long)bz * 32 + bx) * LL + by * BM + tid] = s;
    }
    u16* dst0 = o0 + (long)bz * osb + (long)(by * BM) * ldo + bx * BN;
    for (int i = tid * 8; i < BM * BN; i += NT * 8) {
      const int rr = i / BN, cc = i % BN;
      short8 val = *(const short8*)&smem[rr * BN + (cc ^ ((rr & 7) << 3))];
      *(short8*)(dst0 + (long)rr * ldo + cc) = val;
    }
  } else if constexpr (EPI == 6) {
    // split-K fout partial: bf16(acc * rlsum[col]) -> plane (kch*8+glz)
#pragma unroll
    for (int n = 0; n < FN; ++n) {
      const int nl = nl0 + n * 16 + fr;
      const float il = lsum[(long)glz * LL + bx * BN + nl];
#pragma unroll
      for (int m = 0; m < FM; ++m)
#pragma unroll
        for (int r = 0; r < 4; ++r) {
          const int ml = ml0 + m * 16 + fq * 4 + r;
          smem[ml * BN + (nl ^ ((ml & 7) << 3))] = f2bf(acc[m][n][r] * il);
        }
    }
    __syncthreads();
    u16* dst0 = o0 + ((long)kch * 8 + glz) * osb + (long)(by * BM) * ldo + bx * BN;
    for (int i = tid * 8; i < BM * BN; i += NT * 8) {
      const int rr = i / BN, cc = i % BN;
      short8 val = *(const short8*)&smem[rr * BN + (cc ^ ((rr & 7) << 3))];
      *(short8*)(dst0 + (long)rr * ldo + cc) = val;
    }
  } else {
    // EPI 2: row-major [m][n] bf16 tile
#pragma unroll
    for (int m = 0; m < FM; ++m)
#pragma unroll
      for (int n = 0; n < FN; ++n) {
        const int nl = nl0 + n * 16 + fr;
#pragma unroll
        for (int r = 0; r < 4; ++r) {
          const int ml = ml0 + m * 16 + fq * 4 + r;
          smem[ml * BN + (nl ^ ((ml & 7) << 3))] = f2bf(acc[m][n][r] * scale);
        }
      }
    __syncthreads();
    u16* dst0 = o0 + (long)bz * osb + (long)(by * BM) * ldo + bx * BN;
    for (int i = tid * 8; i < BM * BN; i += NT * 8) {
      const int rr = i / BN, cc = i % BN;
      short8 val = *(const short8*)&smem[rr * BN + (cc ^ ((rr & 7) << 3))];
      *(short8*)(dst0 + (long)rr * ldo + cc) = val;
    }
  }
}

// ---------------------------------------------------------------------------
// K4: rlsum[z][i] = 1 / sum_bx spp[z][bx][i]
// ---------------------------------------------------------------------------
__global__ __launch_bounds__(256) void rlsum_k(const float* __restrict__ spp,
                                               float* __restrict__ rls) {
  const int row = blockIdx.x * 256 + threadIdx.x;     // 0..4095
  const int z = blockIdx.y;
  const float* b = spp + (long)z * 32 * LL + row;
  float s = 0.f;
#pragma unroll
  for (int j = 0; j < 32; ++j) s += b[(long)j * LL];
  rls[(long)z * LL + row] = 1.0f / s;
}

// ---------------------------------------------------------------------------
// K5: out = x + bo + (p0 + p1)   (partials already normalized by rlsum)
// ---------------------------------------------------------------------------
__global__ __launch_bounds__(256) void reduce_out(
    const u16* __restrict__ p0, const u16* __restrict__ p1,
    const float* __restrict__ x, const float* __restrict__ bo,
    float* __restrict__ out) {
  const int gl = blockIdx.y;
  const long idx = (long)blockIdx.x * 256 + threadIdx.x;   // 0..256K-1
  const int o = (int)(idx >> 9);
  const int i0 = ((int)idx & 511) * 8;
  const long base = (long)gl * ((long)LL * CB) + (long)o * LL + i0;
  short8 a = *(const short8*)(p0 + base);
  short8 b = *(const short8*)(p1 + base);
  const float bias = bo[o];
  float4 x0 = *(const float4*)(x + base);
  float4 x1 = *(const float4*)(x + base + 4);
  float4 r0, r1;
  r0.x = x0.x + bias + bf2f((u16)a[0]) + bf2f((u16)b[0]);
  r0.y = x0.y + bias + bf2f((u16)a[1]) + bf2f((u16)b[1]);
  r0.z = x0.z + bias + bf2f((u16)a[2]) + bf2f((u16)b[2]);
  r0.w = x0.w + bias + bf2f((u16)a[3]) + bf2f((u16)b[3]);
  r1.x = x1.x + bias + bf2f((u16)a[4]) + bf2f((u16)b[4]);
  r1.y = x1.y + bias + bf2f((u16)a[5]) + bf2f((u16)b[5]);
  r1.z = x1.z + bias + bf2f((u16)a[6]) + bf2f((u16)b[6]);
  r1.w = x1.w + bias + bf2f((u16)a[7]) + bf2f((u16)b[7]);
  *(float4*)(out + base) = r0;
  *(float4*)(out + base + 4) = r1;
}

// ---------------------------------------------------------------------------
extern "C" void kernel_launch(void* const* d_in, const int* in_sizes, int n_in,
                              void* d_out, int out_size, void* d_ws, size_t ws_size,
                              hipStream_t stream) {
  const float* x   = (const float*)d_in[0];
  const float* gnw = (const float*)d_in[1];
  const float* gnb = (const float*)d_in[2];
  const float* wq  = (const float*)d_in[3];
  const float* bq  = (const float*)d_in[4];
  const float* wk  = (const float*)d_in[5];
  const float* bk  = (const float*)d_in[6];
  const float* wv  = (const float*)d_in[7];
  const float* bv  = (const float*)d_in[8];
  const float* wo  = (const float*)d_in[9];
  const float* bo  = (const float*)d_in[10];
  float* out = (float*)d_out;

  char* ws = (char*)d_ws;
  const long NEL = (long)LL * CB;          // 2M elems = 4 MB bf16 per batch-plane
  const long SEL = (long)LL * LL;          // 16M elems = 32 MB bf16 per batch S
  float* stats = (float*)ws;                               // 8 KB
  float* bqkv  = (float*)(ws + 8192);                      // 6 KB
  u16* wqkv = (u16*)(ws + 16384);                          // 1.5 MB (dead after QKV)
  u16* wob  = (u16*)(ws + 16384 + 1572864);                // 0.5 MB (dead after W)
  u16* hT   = (u16*)(ws + (4l << 20));                     // 32 MB  [B][L][C]; = W after QKV
  u16* qT   = hT + 8 * NEL;                                // 32 MB  [B][L][C]
  u16* kT   = qT + 8 * NEL;                                // 32 MB  [B][L][C]
  u16* vT   = kT + 8 * NEL;                                // 32 MB  [B][L][C]
  u16* W    = hT;                                          // W[b][o][j], hT dead after QKV
  // spp/rlsum overlay the dead wqkv region (1 MB + 32 KB < 1.5 MB)
  float* spp  = (float*)(ws + 16384);                      // [G][32][4096] fp32
  float* rlsm = (float*)(ws + 16384 + (1 << 20));          // [G][4096] fp32
  const size_t base = (4ul << 20) + 4ul * 8 * NEL * 2;     // 132 MB
  const int G = (ws_size >= base + 2ul * SEL * 2 + (1ul << 16)) ? 2 : 1;
  u16* Sbuf = (G == 2) ? (u16*)(ws + base) : vT;           // vT dead after W-GEMM

  conv_w<<<1025, 256, 0, stream>>>(wq, wk, wv, wo, bq, bk, bv, wqkv, wob, bqkv);
  gn_stats<<<256, 256, 0, stream>>>(x, stats);
  gn_apply<<<dim3(64, 8, 8), 256, 0, stream>>>(x, gnw, gnb, stats, hT);

  // fused QKV: A=wqkv [1536][512], Bt=hT[b] [4096][512]; q,k,v all -> [l][c]
  gemm_bt<128, 128, 0, false, false, 2, 2><<<dim3(32, 12, 8), 256, 0, stream>>>(
      wqkv, 512, 0, hT, 512, NEL, 512, bqkv, 1.f, qT, kT, vT,
      nullptr, nullptr, nullptr, 0, 0, 1);

  // W[b] = wo * v[b]: A=wob [512][512], Bt=vT[b] [4096][512]; M=512 N=4096 K=512
  gemm_bt<128, 128, 2, false, false, 2, 2><<<dim3(32, 4, 8), 256, 0, stream>>>(
      wob, 512, 0, vT, 512, NEL, 512, nullptr, 1.f,
      W, nullptr, nullptr, nullptr, nullptr, nullptr, NEL, LL, 1);

  // scale folded with log2(e): p = exp2(S * scal * log2e)
  const float cl = (1.0f / sqrtf(512.0f)) * 1.44269504f;
  for (int g0 = 0; g0 < 8; g0 += G) {
    // expS[z] = exp2(cl * qT * kT^T) bf16 + per-block row sums -> spp
    gemm_bt<128, 128, 5, true, false, 2, 2><<<dim3(32, 32, G), 256, 0, stream>>>(
        qT + (long)g0 * NEL, 512, NEL, kT + (long)g0 * NEL, 512, NEL, 512,
        nullptr, cl, Sbuf, nullptr, nullptr, spp, nullptr, nullptr, SEL, LL, G);
    // rlsum[z][i] = 1/sum
    rlsum_k<<<dim3(16, G), 256, 0, stream>>>(spp, rlsm);
    // fout split-K=2: partial[chunk][gl][o][i] = bf16((W*expS-chunk)*rlsum[i])
    //   chunk0 -> qT+(g0+gl), chunk1 -> kT+(g0+gl)  (dead planes of this pair)
    gemm_bt<64, 128, 6, false, true, 2, 4><<<dim3(8, 32, 2 * G), 512, 0, stream>>>(
        W + (long)g0 * NEL, LL, NEL, Sbuf, LL, SEL, 2048, nullptr, 1.f,
        qT + (long)g0 * NEL, nullptr, nullptr, nullptr, nullptr, rlsm, NEL, LL, G);
    // out = x + bo + p0 + p1
    reduce_out<<<dim3(1024, G), 256, 0, stream>>>(
        qT + (long)g0 * NEL, kT + (long)g0 * NEL,
        x + (long)g0 * NEL, bo, out + (long)g0 * NEL);
  }

  (void)in_sizes; (void)n_in; (void)out_size; (void)ws_size;
}

// Round 8
// 687.696 us; speedup vs baseline: 1.1964x; 1.1770x over previous
//
#include <hip/hip_runtime.h>
#include <hip/hip_bf16.h>
#include <math.h>

#define DI __device__ __forceinline__

typedef unsigned short u16;
typedef unsigned int   u32;
typedef unsigned long long u64;
typedef __attribute__((ext_vector_type(8))) short short8;   // 8 bf16 (4 VGPRs) MFMA A/B frag
typedef __attribute__((ext_vector_type(4))) float f32x4;    // MFMA C/D frag

constexpr int CB = 512;    // channels
constexpr int LL = 4096;   // length
constexpr int NG = 32;     // groups

DI float bf2f(u16 u) { u32 v = ((u32)u) << 16; float f; __builtin_memcpy(&f, &v, 4); return f; }
DI u16 f2bf(float f) {
  u32 u; __builtin_memcpy(&u, &f, 4);
  u += 0x7fffu + ((u >> 16) & 1u);   // RNE
  return (u16)(u >> 16);
}

DI void gload16(const void* g, void* l) {
  __builtin_amdgcn_global_load_lds((const __attribute__((address_space(1))) u32*)g,
                                   (__attribute__((address_space(3))) u32*)l, 16, 0, 0);
}

// ---------------------------------------------------------------------------
// K0: weights -> bf16 (wqkv fused [1536][512], wo [512][512]); fused bias.
// ---------------------------------------------------------------------------
__global__ __launch_bounds__(256) void conv_w(
    const float* __restrict__ wq, const float* __restrict__ wk,
    const float* __restrict__ wv, const float* __restrict__ wo,
    const float* __restrict__ bq, const float* __restrict__ bk,
    const float* __restrict__ bv,
    u16* __restrict__ wqkv, u16* __restrict__ wob, float* __restrict__ bqkv) {
  if (blockIdx.x < 1024) {
    int i = blockIdx.x * 256 + threadIdx.x;
    wqkv[i]          = f2bf(wq[i]);
    wqkv[262144 + i] = f2bf(wk[i]);
    wqkv[524288 + i] = f2bf(wv[i]);
    wob[i]           = f2bf(wo[i]);
  } else {
    for (int j = 0; j < 6; ++j) {
      int idx = j * 256 + threadIdx.x;
      float b = (idx < 512) ? bq[idx] : (idx < 1024) ? bk[idx - 512] : bv[idx - 1024];
      bqkv[idx] = b;
    }
  }
}

// ---------------------------------------------------------------------------
// K1: GroupNorm stats. One block per (b,g).
// ---------------------------------------------------------------------------
__global__ __launch_bounds__(256) void gn_stats(const float* __restrict__ x,
                                                float* __restrict__ stats) {
  const float4* base = (const float4*)(x + (long)blockIdx.x * (16 * LL));
  float s = 0.f, ss = 0.f;
  for (int i = threadIdx.x; i < 16 * LL / 4; i += 256) {
    float4 v = base[i];
    s  += v.x + v.y + v.z + v.w;
    ss += v.x * v.x + v.y * v.y + v.z * v.z + v.w * v.w;
  }
#pragma unroll
  for (int o = 32; o; o >>= 1) { s += __shfl_xor(s, o); ss += __shfl_xor(ss, o); }
  __shared__ float red[8];
  int wv = threadIdx.x >> 6, ln = threadIdx.x & 63;
  if (ln == 0) { red[wv * 2] = s; red[wv * 2 + 1] = ss; }
  __syncthreads();
  if (threadIdx.x == 0) {
    float S = red[0] + red[2] + red[4] + red[6];
    float SS = red[1] + red[3] + red[5] + red[7];
    float mu = S * (1.f / 65536.f);
    float var = SS * (1.f / 65536.f) - mu * mu;
    stats[blockIdx.x * 2]     = mu;
    stats[blockIdx.x * 2 + 1] = rsqrtf(var + 1e-6f);
  }
}

// ---------------------------------------------------------------------------
// K2: GroupNorm apply + transpose: hT[b][l][c] = bf16(gn(x[b][c][l]))
// ---------------------------------------------------------------------------
__global__ __launch_bounds__(256) void gn_apply(
    const float* __restrict__ x, const float* __restrict__ gw,
    const float* __restrict__ gb, const float* __restrict__ stats,
    u16* __restrict__ hT) {
  __shared__ u16 t[64][66];
  const int b = blockIdx.z, c0 = blockIdx.y * 64, l0 = blockIdx.x * 64;
  const int ln = threadIdx.x & 63, sub = threadIdx.x >> 6;
  for (int cr = sub; cr < 64; cr += 4) {
    int c = c0 + cr;
    float v  = x[(long)b * CB * LL + (long)c * LL + l0 + ln];
    float mu = stats[(b * NG + (c >> 4)) * 2];
    float rs = stats[(b * NG + (c >> 4)) * 2 + 1];
    t[cr][ln] = f2bf((v - mu) * rs * gw[c] + gb[c]);
  }
  __syncthreads();
  for (int lr = sub; lr < 64; lr += 4)
    hT[(long)b * LL * CB + (long)(l0 + lr) * CB + c0 + ln] = t[ln][lr];
}

// ---------------------------------------------------------------------------
// Shared GEMM skeleton: D[M][N] = A[M][K] * Bt[N][K]^T  (both k-contiguous)
// BK=64, WR x WC waves (wave tile (BM/WR)x(BN/WC)), 16x16x32 bf16 MFMA,
// LDS XOR-swizzled staging (linear global_load_lds dest + pre-swizzled
// global source — rule #21).
// EPI: 0=QKV (q/k stored transposed [l][c], v natural [c][l]; +bias)
//      1=S (bf16, *scale, z-stride osb)  2=PV plain (bf16, z-stride osb)
//      3=out (fp32 +bias +residual)
//      4=PV split-K: blockIdx.z = (g<<1)|chunk; K=chunk len; partial bf16
//        tile -> (chunk? o1 : o0) + g*LL*CB  (dead qT/kT planes)
// SWZ: bijective XCD-chunked blockIdx swizzle (requires nwg%8==0).
// ---------------------------------------------------------------------------
template <int BM, int BN, int EPI, bool SWZ, int WR, int WC>
__global__ __launch_bounds__(WR * WC * 64) void gemm_bt(
    const u16* __restrict__ A, int lda, long asb,
    const u16* __restrict__ Bt, int ldb, long bsb,
    int K, const float* __restrict__ bias, float scale,
    u16* __restrict__ o0, u16* __restrict__ o1, u16* __restrict__ o2,
    float* __restrict__ of, const float* __restrict__ xres, long osb, int ldo) {
  constexpr int NT = WR * WC * 64;
  constexpr int FM = BM / WR / 16, FN = BN / WC / 16;
  static_assert((BM * 8) % NT == 0 && (BN * 8) % NT == 0, "staging div");
  __shared__ u16 smem[(BM + BN) * 64];
  u16* lA = smem;
  u16* lB = smem + BM * 64;

  int bx = blockIdx.x, by = blockIdx.y;
  if constexpr (SWZ) {
    const int nwg = gridDim.x * gridDim.y;
    const int id = by * gridDim.x + bx;
    const int id2 = (id & 7) * (nwg >> 3) + (id >> 3);
    bx = id2 % gridDim.x;
    by = id2 / gridDim.x;
  }

  const int tid = threadIdx.x;
  const int lane = tid & 63;
  const int wv = tid >> 6;
  const int wr = wv / WC, wc = wv % WC;
  const int fr = lane & 15, fq = lane >> 4;
  const int bz = blockIdx.z;
  const int bzb  = (EPI == 4) ? (bz >> 1) : bz;     // batch index
  const int kbeg = (EPI == 4) ? (bz & 1) * K : 0;   // split-K chunk start

  const u16* Ab = A + (long)bzb * asb + (long)(by * BM) * lda;
  const u16* Bb = Bt + (long)bzb * bsb + (long)(bx * BN) * ldb;

  f32x4 acc[FM][FN];
#pragma unroll
  for (int m = 0; m < FM; ++m)
#pragma unroll
    for (int n = 0; n < FN; ++n) acc[m][n] = (f32x4)(0.f);

  for (int k0 = kbeg; k0 < kbeg + K; k0 += 64) {
#pragma unroll
    for (int p = 0; p < BM * 8 / NT; ++p) {
      int t = p * NT + tid;
      int row = t >> 3;
      int cbl = ((t & 7) << 4) ^ ((row & 7) << 4);     // inverse-swizzled source col (bytes)
      gload16(Ab + (long)row * lda + k0 + (cbl >> 1), &lA[t * 8]);
    }
#pragma unroll
    for (int p = 0; p < BN * 8 / NT; ++p) {
      int t = p * NT + tid;
      int row = t >> 3;
      int cbl = ((t & 7) << 4) ^ ((row & 7) << 4);
      gload16(Bb + (long)row * ldb + k0 + (cbl >> 1), &lB[t * 8]);
    }
    __syncthreads();
#pragma unroll
    for (int ks = 0; ks < 2; ++ks) {
      short8 af[FM], bfr[FN];
#pragma unroll
      for (int m = 0; m < FM; ++m) {
        int row = wr * (BM / WR) + m * 16 + fr;
        int cb = (ks * 64 + fq * 16) ^ ((row & 7) << 4);
        af[m] = *(const short8*)((const char*)lA + row * 128 + cb);
      }
#pragma unroll
      for (int n = 0; n < FN; ++n) {
        int row = wc * (BN / WC) + n * 16 + fr;
        int cb = (ks * 64 + fq * 16) ^ ((row & 7) << 4);
        bfr[n] = *(const short8*)((const char*)lB + row * 128 + cb);
      }
#pragma unroll
      for (int m = 0; m < FM; ++m)
#pragma unroll
        for (int n = 0; n < FN; ++n)
          acc[m][n] = __builtin_amdgcn_mfma_f32_16x16x32_bf16(af[m], bfr[n], acc[m][n], 0, 0, 0);
    }
    __syncthreads();
  }

  const int ml0 = wr * (BM / WR);
  const int nl0 = wc * (BN / WC);

  if constexpr (EPI == 3) {
    const int mg0 = by * BM + ml0;
    const int ng0 = bx * BN + nl0;
#pragma unroll
    for (int m = 0; m < FM; ++m)
#pragma unroll
      for (int n = 0; n < FN; ++n) {
        const int ng = ng0 + n * 16 + fr;
#pragma unroll
        for (int r = 0; r < 4; ++r) {
          const int mg = mg0 + m * 16 + fq * 4 + r;
          const long off = (long)bz * osb + (long)mg * ldo + ng;
          of[off] = acc[m][n][r] + bias[mg] + xres[off];
        }
      }
  } else if constexpr (EPI == 0) {
    const int mat = (by * BM) >> 9;
    if (mat < 2) {
      // q/k: transposed tile in LDS: row = l (nl), col = c (ml), width BM
#pragma unroll
      for (int m = 0; m < FM; ++m)
#pragma unroll
        for (int n = 0; n < FN; ++n) {
          const int nl = nl0 + n * 16 + fr;
#pragma unroll
          for (int r = 0; r < 4; ++r) {
            const int ml = ml0 + m * 16 + fq * 4 + r;
            smem[nl * BM + (ml ^ ((nl & 7) << 3))] =
                f2bf(acc[m][n][r] + bias[by * BM + ml]);
          }
        }
      __syncthreads();
      u16* dst0 = (mat == 0 ? o0 : o1) + (long)bz * ((long)LL * CB) +
                  (long)(bx * BN) * CB + ((by * BM) & 511);
      for (int i = tid * 8; i < BM * BN; i += NT * 8) {
        const int rr = i / BM, cc = i % BM;
        short8 val = *(const short8*)&smem[rr * BM + (cc ^ ((rr & 7) << 3))];
        *(short8*)(dst0 + (long)rr * CB + cc) = val;
      }
    } else {
      // v: natural tile: row = c (ml), col = l (nl), width BN
#pragma unroll
      for (int m = 0; m < FM; ++m)
#pragma unroll
        for (int n = 0; n < FN; ++n) {
          const int nl = nl0 + n * 16 + fr;
#pragma unroll
          for (int r = 0; r < 4; ++r) {
            const int ml = ml0 + m * 16 + fq * 4 + r;
            smem[ml * BN + (nl ^ ((ml & 7) << 3))] =
                f2bf(acc[m][n][r] + bias[by * BM + ml]);
          }
        }
      __syncthreads();
      u16* dst0 = o2 + (long)bz * ((long)CB * LL) +
                  (long)((by * BM) & 511) * LL + bx * BN;
      for (int i = tid * 8; i < BM * BN; i += NT * 8) {
        const int rr = i / BN, cc = i % BN;
        short8 val = *(const short8*)&smem[rr * BN + (cc ^ ((rr & 7) << 3))];
        *(short8*)(dst0 + (long)rr * LL + cc) = val;
      }
    }
  } else if constexpr (EPI == 4) {
    // split-K PV partial -> (chunk? o1 : o0) + g*LL*CB, bf16 row-major
#pragma unroll
    for (int m = 0; m < FM; ++m)
#pragma unroll
      for (int n = 0; n < FN; ++n) {
        const int nl = nl0 + n * 16 + fr;
#pragma unroll
        for (int r = 0; r < 4; ++r) {
          const int ml = ml0 + m * 16 + fq * 4 + r;
          smem[ml * BN + (nl ^ ((ml & 7) << 3))] = f2bf(acc[m][n][r]);
        }
      }
    __syncthreads();
    u16* dst0 = ((bz & 1) ? o1 : o0) + (long)(bz >> 1) * ((long)LL * CB) +
                (long)(by * BM) * ldo + bx * BN;
    for (int i = tid * 8; i < BM * BN; i += NT * 8) {
      const int rr = i / BN, cc = i % BN;
      short8 val = *(const short8*)&smem[rr * BN + (cc ^ ((rr & 7) << 3))];
      *(short8*)(dst0 + (long)rr * ldo + cc) = val;
    }
  } else {
    // EPI 1/2: row-major [m][n] bf16 tile (scaled)
#pragma unroll
    for (int m = 0; m < FM; ++m)
#pragma unroll
      for (int n = 0; n < FN; ++n) {
        const int nl = nl0 + n * 16 + fr;
#pragma unroll
        for (int r = 0; r < 4; ++r) {
          const int ml = ml0 + m * 16 + fq * 4 + r;
          smem[ml * BN + (nl ^ ((ml & 7) << 3))] = f2bf(acc[m][n][r] * scale);
        }
      }
    __syncthreads();
    u16* dst0 = o0 + (long)bz * osb + (long)(by * BM) * ldo + bx * BN;
    for (int i = tid * 8; i < BM * BN; i += NT * 8) {
      const int rr = i / BN, cc = i % BN;
      short8 val = *(const short8*)&smem[rr * BN + (cc ^ ((rr & 7) << 3))];
      *(short8*)(dst0 + (long)rr * ldo + cc) = val;
    }
  }
}

// ---------------------------------------------------------------------------
// K4: row softmax in-place on bf16 S [G][4096][4096]; block = one row.
// ---------------------------------------------------------------------------
__global__ __launch_bounds__(256) void softmax_row(u16* __restrict__ S) {
  u16* row = S + ((long)blockIdx.y * LL + blockIdx.x) * LL;
  const int tid = threadIdx.x;
  const int wv = tid >> 6, ln = tid & 63;
  short8 a = ((const short8*)row)[tid * 2];
  short8 b = ((const short8*)row)[tid * 2 + 1];
  float v[16];
#pragma unroll
  for (int j = 0; j < 8; ++j) { v[j] = bf2f((u16)a[j]); v[8 + j] = bf2f((u16)b[j]); }
  float mx = -1e30f;
#pragma unroll
  for (int j = 0; j < 16; ++j) mx = fmaxf(mx, v[j]);
#pragma unroll
  for (int o = 32; o; o >>= 1) mx = fmaxf(mx, __shfl_xor(mx, o));
  __shared__ float red[4];
  if (ln == 0) red[wv] = mx;
  __syncthreads();
  mx = fmaxf(fmaxf(red[0], red[1]), fmaxf(red[2], red[3]));
  __syncthreads();
  float sum = 0.f;
#pragma unroll
  for (int j = 0; j < 16; ++j) { v[j] = __expf(v[j] - mx); sum += v[j]; }
#pragma unroll
  for (int o = 32; o; o >>= 1) sum += __shfl_xor(sum, o);
  if (ln == 0) red[wv] = sum;
  __syncthreads();
  sum = red[0] + red[1] + red[2] + red[3];
  const float r = 1.f / sum;
  short8 o1, o2;
#pragma unroll
  for (int j = 0; j < 8; ++j) { o1[j] = (short)f2bf(v[j] * r); o2[j] = (short)f2bf(v[8 + j] * r); }
  ((short8*)row)[tid * 2] = o1;
  ((short8*)row)[tid * 2 + 1] = o2;
}

// ---------------------------------------------------------------------------
// K5: sum two bf16 partial planes -> bf16 out plane.  grid (512, G).
// ---------------------------------------------------------------------------
__global__ __launch_bounds__(256) void reduce_pp(
    const u16* __restrict__ p0, const u16* __restrict__ p1, u16* __restrict__ o) {
  const long base = (long)blockIdx.y * ((long)LL * CB) +
                    (long)(blockIdx.x * 256 + threadIdx.x) * 16;
#pragma unroll
  for (int h = 0; h < 2; ++h) {
    short8 a = *(const short8*)(p0 + base + h * 8);
    short8 b = *(const short8*)(p1 + base + h * 8);
    short8 r;
#pragma unroll
    for (int j = 0; j < 8; ++j)
      r[j] = (short)f2bf(bf2f((u16)a[j]) + bf2f((u16)b[j]));
    *(short8*)(o + base + h * 8) = r;
  }
}

// ---------------------------------------------------------------------------
extern "C" void kernel_launch(void* const* d_in, const int* in_sizes, int n_in,
                              void* d_out, int out_size, void* d_ws, size_t ws_size,
                              hipStream_t stream) {
  const float* x   = (const float*)d_in[0];
  const float* gnw = (const float*)d_in[1];
  const float* gnb = (const float*)d_in[2];
  const float* wq  = (const float*)d_in[3];
  const float* bq  = (const float*)d_in[4];
  const float* wk  = (const float*)d_in[5];
  const float* bk  = (const float*)d_in[6];
  const float* wv  = (const float*)d_in[7];
  const float* bv  = (const float*)d_in[8];
  const float* wo  = (const float*)d_in[9];
  const float* bo  = (const float*)d_in[10];
  float* out = (float*)d_out;

  char* ws = (char*)d_ws;
  const long NEL = (long)LL * CB;          // 2M elems = 4 MB bf16 per batch-plane
  const long SEL = (long)LL * LL;          // 16M elems = 32 MB bf16 per batch S
  float* stats = (float*)ws;                               // 8 KB
  float* bqkv  = (float*)(ws + 8192);                      // 6 KB
  u16* wqkv = (u16*)(ws + 16384);                          // 1.5 MB
  u16* wob  = (u16*)(ws + 16384 + 1572864);                // 0.5 MB
  u16* hT   = (u16*)(ws + (4l << 20));                     // 32 MB  [B][L][C]
  u16* qT   = hT + 8 * NEL;                                // 32 MB  [B][L][C]
  u16* kT   = qT + 8 * NEL;                                // 32 MB  [B][L][C]
  u16* vN   = kT + 8 * NEL;                                // 32 MB  [B][C][L]
  const size_t base = (4ul << 20) + 4ul * 8 * NEL * 2;     // 132 MB

  // G = attention batches per round (S buffer = G*32 MB beyond base).
  int G;
  u16 *Sbuf, *aT;
  if (ws_size >= base + 2ul * SEL * 2) G = 2;
  else                                 G = 1;
  if (G > 1) { Sbuf = (u16*)(ws + base); aT = hT; }        // hT dead after QKV
  else       { Sbuf = hT; aT = qT; }                       // legacy aliasing

  conv_w<<<1025, 256, 0, stream>>>(wq, wk, wv, wo, bq, bk, bv, wqkv, wob, bqkv);
  gn_stats<<<256, 256, 0, stream>>>(x, stats);
  gn_apply<<<dim3(64, 8, 8), 256, 0, stream>>>(x, gnw, gnb, stats, hT);

  // fused QKV: A=wqkv [1536][512], Bt=hT[b] [4096][512]
  gemm_bt<128, 128, 0, true, 2, 2><<<dim3(32, 12, 8), 256, 0, stream>>>(
      wqkv, 512, 0, hT, 512, NEL, 512, bqkv, 1.f, qT, kT, vN, nullptr, nullptr, 0, 0);

  const float scal = 1.0f / sqrtf(512.0f);
  for (int g0 = 0; g0 < 8; g0 += G) {
    // S[z] = scale * qT[g0+z] * kT[g0+z]^T : M=N=4096, K=512
    gemm_bt<128, 128, 1, true, 2, 2><<<dim3(32, 32, G), 256, 0, stream>>>(
        qT + (long)g0 * NEL, 512, NEL, kT + (long)g0 * NEL, 512, NEL, 512,
        nullptr, scal, Sbuf, nullptr, nullptr, nullptr, nullptr, SEL, LL);
    softmax_row<<<dim3(LL, G), 256, 0, stream>>>(Sbuf);
    if (G == 2) {
      // PV split-K, 8 waves/block: partials -> dead qT/kT planes, then reduce.
      gemm_bt<128, 128, 4, true, 2, 4><<<dim3(4, 32, 4), 512, 0, stream>>>(
          Sbuf, LL, SEL, vN + (long)g0 * NEL, LL, NEL, 2048,
          nullptr, 1.f, qT + (long)g0 * NEL, kT + (long)g0 * NEL, nullptr,
          nullptr, nullptr, 0, CB);
      reduce_pp<<<dim3(512, 2), 256, 0, stream>>>(
          qT + (long)g0 * NEL, kT + (long)g0 * NEL, aT + (long)g0 * NEL);
    } else {
      gemm_bt<128, 64, 2, true, 2, 2><<<dim3(8, 32, 1), 256, 0, stream>>>(
          Sbuf, LL, 0, vN + (long)g0 * NEL, LL, 0, LL,
          nullptr, 1.f, aT + (long)g0 * NEL, nullptr, nullptr, nullptr, nullptr, NEL, CB);
    }
  }

  // out = x + wo * attnT^T + bo : M=512, N=4096, K=512 per batch
  gemm_bt<128, 128, 3, true, 2, 2><<<dim3(32, 4, 8), 256, 0, stream>>>(
      wob, 512, 0, aT, 512, NEL, 512, bo, 1.f,
      nullptr, nullptr, nullptr, out, x, NEL, LL);

  (void)in_sizes; (void)n_in; (void)out_size; (void)ws_size;
}

// Round 9
// 627.572 us; speedup vs baseline: 1.3110x; 1.0958x over previous
//
#include <hip/hip_runtime.h>
#include <hip/hip_bf16.h>
#include <math.h>

#define DI __device__ __forceinline__

typedef unsigned short u16;
typedef unsigned int   u32;
typedef unsigned long long u64;
typedef __attribute__((ext_vector_type(8))) short short8;   // 8 bf16 (4 VGPRs) MFMA A/B frag
typedef __attribute__((ext_vector_type(4))) float f32x4;    // MFMA C/D frag

constexpr int CB = 512;    // channels
constexpr int LL = 4096;   // length
constexpr int NG = 32;     // groups

DI float bf2f(u16 u) { u32 v = ((u32)u) << 16; float f; __builtin_memcpy(&f, &v, 4); return f; }
DI u16 f2bf(float f) {
  u32 u; __builtin_memcpy(&u, &f, 4);
  u += 0x7fffu + ((u >> 16) & 1u);   // RNE
  return (u16)(u >> 16);
}

DI void gload16(const void* g, void* l) {
  __builtin_amdgcn_global_load_lds((const __attribute__((address_space(1))) u32*)g,
                                   (__attribute__((address_space(3))) u32*)l, 16, 0, 0);
}

// ---------------------------------------------------------------------------
// K0: weights -> bf16 (wqkv fused [1536][512], wo [512][512]); fused bias.
// ---------------------------------------------------------------------------
__global__ __launch_bounds__(256) void conv_w(
    const float* __restrict__ wq, const float* __restrict__ wk,
    const float* __restrict__ wv, const float* __restrict__ wo,
    const float* __restrict__ bq, const float* __restrict__ bk,
    const float* __restrict__ bv,
    u16* __restrict__ wqkv, u16* __restrict__ wob, float* __restrict__ bqkv) {
  if (blockIdx.x < 1024) {
    int i = blockIdx.x * 256 + threadIdx.x;
    wqkv[i]          = f2bf(wq[i]);
    wqkv[262144 + i] = f2bf(wk[i]);
    wqkv[524288 + i] = f2bf(wv[i]);
    wob[i]           = f2bf(wo[i]);
  } else {
    for (int j = 0; j < 6; ++j) {
      int idx = j * 256 + threadIdx.x;
      float b = (idx < 512) ? bq[idx] : (idx < 1024) ? bk[idx - 512] : bv[idx - 1024];
      bqkv[idx] = b;
    }
  }
}

// ---------------------------------------------------------------------------
// K1: GroupNorm stats. One block per (b,g).
// ---------------------------------------------------------------------------
__global__ __launch_bounds__(256) void gn_stats(const float* __restrict__ x,
                                                float* __restrict__ stats) {
  const float4* base = (const float4*)(x + (long)blockIdx.x * (16 * LL));
  float s = 0.f, ss = 0.f;
  for (int i = threadIdx.x; i < 16 * LL / 4; i += 256) {
    float4 v = base[i];
    s  += v.x + v.y + v.z + v.w;
    ss += v.x * v.x + v.y * v.y + v.z * v.z + v.w * v.w;
  }
#pragma unroll
  for (int o = 32; o; o >>= 1) { s += __shfl_xor(s, o); ss += __shfl_xor(ss, o); }
  __shared__ float red[8];
  int wv = threadIdx.x >> 6, ln = threadIdx.x & 63;
  if (ln == 0) { red[wv * 2] = s; red[wv * 2 + 1] = ss; }
  __syncthreads();
  if (threadIdx.x == 0) {
    float S = red[0] + red[2] + red[4] + red[6];
    float SS = red[1] + red[3] + red[5] + red[7];
    float mu = S * (1.f / 65536.f);
    float var = SS * (1.f / 65536.f) - mu * mu;
    stats[blockIdx.x * 2]     = mu;
    stats[blockIdx.x * 2 + 1] = rsqrtf(var + 1e-6f);
  }
}

// ---------------------------------------------------------------------------
// K2: GroupNorm apply + transpose: hT[b][l][c] = bf16(gn(x[b][c][l]))
// ---------------------------------------------------------------------------
__global__ __launch_bounds__(256) void gn_apply(
    const float* __restrict__ x, const float* __restrict__ gw,
    const float* __restrict__ gb, const float* __restrict__ stats,
    u16* __restrict__ hT) {
  __shared__ u16 t[64][66];
  const int b = blockIdx.z, c0 = blockIdx.y * 64, l0 = blockIdx.x * 64;
  const int ln = threadIdx.x & 63, sub = threadIdx.x >> 6;
  for (int cr = sub; cr < 64; cr += 4) {
    int c = c0 + cr;
    float v  = x[(long)b * CB * LL + (long)c * LL + l0 + ln];
    float mu = stats[(b * NG + (c >> 4)) * 2];
    float rs = stats[(b * NG + (c >> 4)) * 2 + 1];
    t[cr][ln] = f2bf((v - mu) * rs * gw[c] + gb[c]);
  }
  __syncthreads();
  for (int lr = sub; lr < 64; lr += 4)
    hT[(long)b * LL * CB + (long)(l0 + lr) * CB + c0 + ln] = t[ln][lr];
}

// ---------------------------------------------------------------------------
// Shared GEMM skeleton: D[M][N] = A[M][K] * Bt[N][K]^T  (both k-contiguous)
// BK=64, WR x WC waves (wave tile (BM/WR)x(BN/WC)), 16x16x32 bf16 MFMA,
// LDS XOR-swizzled staging (linear global_load_lds dest + pre-swizzled
// global source — rule #21).
// EPI: 0=QKV (q/k stored transposed [l][c], v natural [c][l]; +bias)
//      1=expS: bf16 tile of exp2(acc*scale)  (no-max softmax numerator)
//      3=out (fp32 +bias +residual)
//      4=PV split-K normalized: blockIdx.z=(g<<1)|chunk; partial bf16 tile
//        of acc*rls[row] -> (chunk? o1 : o0) + g*LL*CB  (dead qT/kT planes);
//        rls passed via xres.
// SWZ: bijective XCD-chunked blockIdx swizzle (requires nwg%8==0).
// ---------------------------------------------------------------------------
template <int BM, int BN, int EPI, bool SWZ, int WR, int WC>
__global__ __launch_bounds__(WR * WC * 64) void gemm_bt(
    const u16* __restrict__ A, int lda, long asb,
    const u16* __restrict__ Bt, int ldb, long bsb,
    int K, const float* __restrict__ bias, float scale,
    u16* __restrict__ o0, u16* __restrict__ o1, u16* __restrict__ o2,
    float* __restrict__ of, const float* __restrict__ xres, long osb, int ldo) {
  constexpr int NT = WR * WC * 64;
  constexpr int FM = BM / WR / 16, FN = BN / WC / 16;
  static_assert((BM * 8) % NT == 0 && (BN * 8) % NT == 0, "staging div");
  __shared__ u16 smem[(BM + BN) * 64];
  u16* lA = smem;
  u16* lB = smem + BM * 64;

  int bx = blockIdx.x, by = blockIdx.y;
  if constexpr (SWZ) {
    const int nwg = gridDim.x * gridDim.y;
    const int id = by * gridDim.x + bx;
    const int id2 = (id & 7) * (nwg >> 3) + (id >> 3);
    bx = id2 % gridDim.x;
    by = id2 / gridDim.x;
  }

  const int tid = threadIdx.x;
  const int lane = tid & 63;
  const int wv = tid >> 6;
  const int wr = wv / WC, wc = wv % WC;
  const int fr = lane & 15, fq = lane >> 4;
  const int bz = blockIdx.z;
  const int bzb  = (EPI == 4) ? (bz >> 1) : bz;     // batch index
  const int kbeg = (EPI == 4) ? (bz & 1) * K : 0;   // split-K chunk start

  const u16* Ab = A + (long)bzb * asb + (long)(by * BM) * lda;
  const u16* Bb = Bt + (long)bzb * bsb + (long)(bx * BN) * ldb;

  f32x4 acc[FM][FN];
#pragma unroll
  for (int m = 0; m < FM; ++m)
#pragma unroll
    for (int n = 0; n < FN; ++n) acc[m][n] = (f32x4)(0.f);

  for (int k0 = kbeg; k0 < kbeg + K; k0 += 64) {
#pragma unroll
    for (int p = 0; p < BM * 8 / NT; ++p) {
      int t = p * NT + tid;
      int row = t >> 3;
      int cbl = ((t & 7) << 4) ^ ((row & 7) << 4);     // inverse-swizzled source col (bytes)
      gload16(Ab + (long)row * lda + k0 + (cbl >> 1), &lA[t * 8]);
    }
#pragma unroll
    for (int p = 0; p < BN * 8 / NT; ++p) {
      int t = p * NT + tid;
      int row = t >> 3;
      int cbl = ((t & 7) << 4) ^ ((row & 7) << 4);
      gload16(Bb + (long)row * ldb + k0 + (cbl >> 1), &lB[t * 8]);
    }
    __syncthreads();
#pragma unroll
    for (int ks = 0; ks < 2; ++ks) {
      short8 af[FM], bfr[FN];
#pragma unroll
      for (int m = 0; m < FM; ++m) {
        int row = wr * (BM / WR) + m * 16 + fr;
        int cb = (ks * 64 + fq * 16) ^ ((row & 7) << 4);
        af[m] = *(const short8*)((const char*)lA + row * 128 + cb);
      }
#pragma unroll
      for (int n = 0; n < FN; ++n) {
        int row = wc * (BN / WC) + n * 16 + fr;
        int cb = (ks * 64 + fq * 16) ^ ((row & 7) << 4);
        bfr[n] = *(const short8*)((const char*)lB + row * 128 + cb);
      }
#pragma unroll
      for (int m = 0; m < FM; ++m)
#pragma unroll
        for (int n = 0; n < FN; ++n)
          acc[m][n] = __builtin_amdgcn_mfma_f32_16x16x32_bf16(af[m], bfr[n], acc[m][n], 0, 0, 0);
    }
    __syncthreads();
  }

  const int ml0 = wr * (BM / WR);
  const int nl0 = wc * (BN / WC);

  if constexpr (EPI == 3) {
    const int mg0 = by * BM + ml0;
    const int ng0 = bx * BN + nl0;
#pragma unroll
    for (int m = 0; m < FM; ++m)
#pragma unroll
      for (int n = 0; n < FN; ++n) {
        const int ng = ng0 + n * 16 + fr;
#pragma unroll
        for (int r = 0; r < 4; ++r) {
          const int mg = mg0 + m * 16 + fq * 4 + r;
          const long off = (long)bz * osb + (long)mg * ldo + ng;
          of[off] = acc[m][n][r] + bias[mg] + xres[off];
        }
      }
  } else if constexpr (EPI == 0) {
    const int mat = (by * BM) >> 9;
    if (mat < 2) {
      // q/k: transposed tile in LDS: row = l (nl), col = c (ml), width BM
#pragma unroll
      for (int m = 0; m < FM; ++m)
#pragma unroll
        for (int n = 0; n < FN; ++n) {
          const int nl = nl0 + n * 16 + fr;
#pragma unroll
          for (int r = 0; r < 4; ++r) {
            const int ml = ml0 + m * 16 + fq * 4 + r;
            smem[nl * BM + (ml ^ ((nl & 7) << 3))] =
                f2bf(acc[m][n][r] + bias[by * BM + ml]);
          }
        }
      __syncthreads();
      u16* dst0 = (mat == 0 ? o0 : o1) + (long)bz * ((long)LL * CB) +
                  (long)(bx * BN) * CB + ((by * BM) & 511);
      for (int i = tid * 8; i < BM * BN; i += NT * 8) {
        const int rr = i / BM, cc = i % BM;
        short8 val = *(const short8*)&smem[rr * BM + (cc ^ ((rr & 7) << 3))];
        *(short8*)(dst0 + (long)rr * CB + cc) = val;
      }
    } else {
      // v: natural tile: row = c (ml), col = l (nl), width BN
#pragma unroll
      for (int m = 0; m < FM; ++m)
#pragma unroll
        for (int n = 0; n < FN; ++n) {
          const int nl = nl0 + n * 16 + fr;
#pragma unroll
          for (int r = 0; r < 4; ++r) {
            const int ml = ml0 + m * 16 + fq * 4 + r;
            smem[ml * BN + (nl ^ ((ml & 7) << 3))] =
                f2bf(acc[m][n][r] + bias[by * BM + ml]);
          }
        }
      __syncthreads();
      u16* dst0 = o2 + (long)bz * ((long)CB * LL) +
                  (long)((by * BM) & 511) * LL + bx * BN;
      for (int i = tid * 8; i < BM * BN; i += NT * 8) {
        const int rr = i / BN, cc = i % BN;
        short8 val = *(const short8*)&smem[rr * BN + (cc ^ ((rr & 7) << 3))];
        *(short8*)(dst0 + (long)rr * LL + cc) = val;
      }
    }
  } else if constexpr (EPI == 4) {
    // split-K PV partial, normalized: bf16(acc * rls[row]) -> chunk plane
    const float* rls = xres + (long)(bz >> 1) * LL + by * BM;
#pragma unroll
    for (int m = 0; m < FM; ++m)
#pragma unroll
      for (int n = 0; n < FN; ++n) {
        const int nl = nl0 + n * 16 + fr;
#pragma unroll
        for (int r = 0; r < 4; ++r) {
          const int ml = ml0 + m * 16 + fq * 4 + r;
          smem[ml * BN + (nl ^ ((ml & 7) << 3))] = f2bf(acc[m][n][r] * rls[ml]);
        }
      }
    __syncthreads();
    u16* dst0 = ((bz & 1) ? o1 : o0) + (long)(bz >> 1) * ((long)LL * CB) +
                (long)(by * BM) * ldo + bx * BN;
    for (int i = tid * 8; i < BM * BN; i += NT * 8) {
      const int rr = i / BN, cc = i % BN;
      short8 val = *(const short8*)&smem[rr * BN + (cc ^ ((rr & 7) << 3))];
      *(short8*)(dst0 + (long)rr * ldo + cc) = val;
    }
  } else {
    // EPI 1: expS tile: bf16(exp2(acc*scale))
#pragma unroll
    for (int m = 0; m < FM; ++m)
#pragma unroll
      for (int n = 0; n < FN; ++n) {
        const int nl = nl0 + n * 16 + fr;
#pragma unroll
        for (int r = 0; r < 4; ++r) {
          const int ml = ml0 + m * 16 + fq * 4 + r;
          smem[ml * BN + (nl ^ ((ml & 7) << 3))] = f2bf(exp2f(acc[m][n][r] * scale));
        }
      }
    __syncthreads();
    u16* dst0 = o0 + (long)bz * osb + (long)(by * BM) * ldo + bx * BN;
    for (int i = tid * 8; i < BM * BN; i += NT * 8) {
      const int rr = i / BN, cc = i % BN;
      short8 val = *(const short8*)&smem[rr * BN + (cc ^ ((rr & 7) << 3))];
      *(short8*)(dst0 + (long)rr * ldo + cc) = val;
    }
  }
}

// ---------------------------------------------------------------------------
// K4: rls[z][i] = 1 / sum_j expS[z][i][j].  One block per row; read-only pass.
// ---------------------------------------------------------------------------
__global__ __launch_bounds__(256) void rsum_rows(const u16* __restrict__ S,
                                                 float* __restrict__ rls) {
  const u16* row = S + ((long)blockIdx.y * LL + blockIdx.x) * LL;
  const int tid = threadIdx.x;
  const int wv = tid >> 6, ln = tid & 63;
  short8 a = ((const short8*)row)[tid * 2];
  short8 b = ((const short8*)row)[tid * 2 + 1];
  float s = 0.f;
#pragma unroll
  for (int j = 0; j < 8; ++j) s += bf2f((u16)a[j]) + bf2f((u16)b[j]);
#pragma unroll
  for (int o = 32; o; o >>= 1) s += __shfl_xor(s, o);
  __shared__ float red[4];
  if (ln == 0) red[wv] = s;
  __syncthreads();
  if (tid == 0)
    rls[(long)blockIdx.y * LL + blockIdx.x] =
        1.0f / (red[0] + red[1] + red[2] + red[3]);
}

// ---------------------------------------------------------------------------
// K5: sum two bf16 partial planes -> bf16 out plane.  grid (512, G).
//     (safe in-place when o == p0: per-thread read-then-write, same index)
// ---------------------------------------------------------------------------
__global__ __launch_bounds__(256) void reduce_pp(
    const u16* __restrict__ p0, const u16* __restrict__ p1, u16* __restrict__ o) {
  const long base = (long)blockIdx.y * ((long)LL * CB) +
                    (long)(blockIdx.x * 256 + threadIdx.x) * 16;
#pragma unroll
  for (int h = 0; h < 2; ++h) {
    short8 a = *(const short8*)(p0 + base + h * 8);
    short8 b = *(const short8*)(p1 + base + h * 8);
    short8 r;
#pragma unroll
    for (int j = 0; j < 8; ++j)
      r[j] = (short)f2bf(bf2f((u16)a[j]) + bf2f((u16)b[j]));
    *(short8*)(o + base + h * 8) = r;
  }
}

// ---------------------------------------------------------------------------
extern "C" void kernel_launch(void* const* d_in, const int* in_sizes, int n_in,
                              void* d_out, int out_size, void* d_ws, size_t ws_size,
                              hipStream_t stream) {
  const float* x   = (const float*)d_in[0];
  const float* gnw = (const float*)d_in[1];
  const float* gnb = (const float*)d_in[2];
  const float* wq  = (const float*)d_in[3];
  const float* bq  = (const float*)d_in[4];
  const float* wk  = (const float*)d_in[5];
  const float* bk  = (const float*)d_in[6];
  const float* wv  = (const float*)d_in[7];
  const float* bv  = (const float*)d_in[8];
  const float* wo  = (const float*)d_in[9];
  const float* bo  = (const float*)d_in[10];
  float* out = (float*)d_out;

  char* ws = (char*)d_ws;
  const long NEL = (long)LL * CB;          // 2M elems = 4 MB bf16 per batch-plane
  const long SEL = (long)LL * LL;          // 16M elems = 32 MB bf16 per batch S
  float* stats = (float*)ws;                               // 8 KB
  float* bqkv  = (float*)(ws + 8192);                      // 6 KB
  u16* wqkv = (u16*)(ws + 16384);                          // 1.5 MB
  u16* wob  = (u16*)(ws + 16384 + 1572864);                // 0.5 MB
  float* rlsm = (float*)(ws + (3l << 20));                 // G*16 KB (scratch gap)
  u16* hT   = (u16*)(ws + (4l << 20));                     // 32 MB  [B][L][C]
  u16* qT   = hT + 8 * NEL;                                // 32 MB  [B][L][C]
  u16* kT   = qT + 8 * NEL;                                // 32 MB  [B][L][C]
  u16* vN   = kT + 8 * NEL;                                // 32 MB  [B][C][L]
  const size_t base = (4ul << 20) + 4ul * 8 * NEL * 2;     // 132 MB

  // G = attention batches per round (S buffer = G*32 MB beyond base).
  int G;
  u16 *Sbuf, *aT;
  if (ws_size >= base + 2ul * SEL * 2) G = 2;
  else                                 G = 1;
  if (G > 1) { Sbuf = (u16*)(ws + base); aT = hT; }        // hT dead after QKV
  else       { Sbuf = hT; aT = qT; }                       // in-place reduce into qT

  conv_w<<<1025, 256, 0, stream>>>(wq, wk, wv, wo, bq, bk, bv, wqkv, wob, bqkv);
  gn_stats<<<256, 256, 0, stream>>>(x, stats);
  gn_apply<<<dim3(64, 8, 8), 256, 0, stream>>>(x, gnw, gnb, stats, hT);

  // fused QKV: A=wqkv [1536][512], Bt=hT[b] [4096][512]  (no swizzle: measured
  // regression 82->91 us, FETCH 47->170 MB with SWZ in round 8)
  gemm_bt<128, 128, 0, false, 2, 2><<<dim3(32, 12, 8), 256, 0, stream>>>(
      wqkv, 512, 0, hT, 512, NEL, 512, bqkv, 1.f, qT, kT, vN, nullptr, nullptr, 0, 0);

  // no-max softmax (numerics proven r6/r7): expS = exp2(cl * q.k), rls = 1/rowsum
  const float cl = (1.0f / sqrtf(512.0f)) * 1.44269504f;
  for (int g0 = 0; g0 < 8; g0 += G) {
    // expS[z] = exp2(cl * qT[g0+z] * kT[g0+z]^T) : M=N=4096, K=512
    gemm_bt<128, 128, 1, false, 2, 2><<<dim3(32, 32, G), 256, 0, stream>>>(
        qT + (long)g0 * NEL, 512, NEL, kT + (long)g0 * NEL, 512, NEL, 512,
        nullptr, cl, Sbuf, nullptr, nullptr, nullptr, nullptr, SEL, LL);
    rsum_rows<<<dim3(LL, G), 256, 0, stream>>>(Sbuf, rlsm);
    // PV split-K, 8 waves/block, normalized partials -> dead qT/kT planes
    gemm_bt<128, 128, 4, true, 2, 4><<<dim3(4, 32, 2 * G), 512, 0, stream>>>(
        Sbuf, LL, SEL, vN + (long)g0 * NEL, LL, NEL, 2048,
        nullptr, 1.f, qT + (long)g0 * NEL, kT + (long)g0 * NEL, nullptr,
        nullptr, rlsm, 0, CB);
    reduce_pp<<<dim3(512, G), 256, 0, stream>>>(
        qT + (long)g0 * NEL, kT + (long)g0 * NEL, aT + (long)g0 * NEL);
  }

  // out = x + wo * attnT^T + bo : M=512, N=4096, K=512 per batch
  gemm_bt<128, 128, 3, false, 2, 2><<<dim3(32, 4, 8), 256, 0, stream>>>(
      wob, 512, 0, aT, 512, NEL, 512, bo, 1.f,
      nullptr, nullptr, nullptr, out, x, NEL, LL);

  (void)in_sizes; (void)n_in; (void)out_size; (void)ws_size;
}

// Round 10
// 618.961 us; speedup vs baseline: 1.3293x; 1.0139x over previous
//
#include <hip/hip_runtime.h>
#include <hip/hip_bf16.h>
#include <math.h>

#define DI __device__ __forceinline__

typedef unsigned short u16;
typedef unsigned int   u32;
typedef unsigned long long u64;
typedef __attribute__((ext_vector_type(8))) short short8;   // 8 bf16 (4 VGPRs) MFMA A/B frag
typedef __attribute__((ext_vector_type(4))) float f32x4;    // MFMA C/D frag

constexpr int CB = 512;    // channels
constexpr int LL = 4096;   // length
constexpr int NG = 32;     // groups

DI float bf2f(u16 u) { u32 v = ((u32)u) << 16; float f; __builtin_memcpy(&f, &v, 4); return f; }
DI u16 f2bf(float f) {
  u32 u; __builtin_memcpy(&u, &f, 4);
  u += 0x7fffu + ((u >> 16) & 1u);   // RNE
  return (u16)(u >> 16);
}

DI void gload16(const void* g, void* l) {
  __builtin_amdgcn_global_load_lds((const __attribute__((address_space(1))) u32*)g,
                                   (__attribute__((address_space(3))) u32*)l, 16, 0, 0);
}

// ---------------------------------------------------------------------------
// K0: weights -> bf16 (wqkv fused [1536][512], wo [512][512]); fused bias.
// ---------------------------------------------------------------------------
__global__ __launch_bounds__(256) void conv_w(
    const float* __restrict__ wq, const float* __restrict__ wk,
    const float* __restrict__ wv, const float* __restrict__ wo,
    const float* __restrict__ bq, const float* __restrict__ bk,
    const float* __restrict__ bv,
    u16* __restrict__ wqkv, u16* __restrict__ wob, float* __restrict__ bqkv) {
  if (blockIdx.x < 1024) {
    int i = blockIdx.x * 256 + threadIdx.x;
    wqkv[i]          = f2bf(wq[i]);
    wqkv[262144 + i] = f2bf(wk[i]);
    wqkv[524288 + i] = f2bf(wv[i]);
    wob[i]           = f2bf(wo[i]);
  } else {
    for (int j = 0; j < 6; ++j) {
      int idx = j * 256 + threadIdx.x;
      float b = (idx < 512) ? bq[idx] : (idx < 1024) ? bk[idx - 512] : bv[idx - 1024];
      bqkv[idx] = b;
    }
  }
}

// ---------------------------------------------------------------------------
// K1: GroupNorm stats. One block per (b,g).
// ---------------------------------------------------------------------------
__global__ __launch_bounds__(256) void gn_stats(const float* __restrict__ x,
                                                float* __restrict__ stats) {
  const float4* base = (const float4*)(x + (long)blockIdx.x * (16 * LL));
  float s = 0.f, ss = 0.f;
  for (int i = threadIdx.x; i < 16 * LL / 4; i += 256) {
    float4 v = base[i];
    s  += v.x + v.y + v.z + v.w;
    ss += v.x * v.x + v.y * v.y + v.z * v.z + v.w * v.w;
  }
#pragma unroll
  for (int o = 32; o; o >>= 1) { s += __shfl_xor(s, o); ss += __shfl_xor(ss, o); }
  __shared__ float red[8];
  int wv = threadIdx.x >> 6, ln = threadIdx.x & 63;
  if (ln == 0) { red[wv * 2] = s; red[wv * 2 + 1] = ss; }
  __syncthreads();
  if (threadIdx.x == 0) {
    float S = red[0] + red[2] + red[4] + red[6];
    float SS = red[1] + red[3] + red[5] + red[7];
    float mu = S * (1.f / 65536.f);
    float var = SS * (1.f / 65536.f) - mu * mu;
    stats[blockIdx.x * 2]     = mu;
    stats[blockIdx.x * 2 + 1] = rsqrtf(var + 1e-6f);
  }
}

// ---------------------------------------------------------------------------
// K2: GroupNorm apply + transpose: hT[b][l][c] = bf16(gn(x[b][c][l]))
// ---------------------------------------------------------------------------
__global__ __launch_bounds__(256) void gn_apply(
    const float* __restrict__ x, const float* __restrict__ gw,
    const float* __restrict__ gb, const float* __restrict__ stats,
    u16* __restrict__ hT) {
  __shared__ u16 t[64][66];
  const int b = blockIdx.z, c0 = blockIdx.y * 64, l0 = blockIdx.x * 64;
  const int ln = threadIdx.x & 63, sub = threadIdx.x >> 6;
  for (int cr = sub; cr < 64; cr += 4) {
    int c = c0 + cr;
    float v  = x[(long)b * CB * LL + (long)c * LL + l0 + ln];
    float mu = stats[(b * NG + (c >> 4)) * 2];
    float rs = stats[(b * NG + (c >> 4)) * 2 + 1];
    t[cr][ln] = f2bf((v - mu) * rs * gw[c] + gb[c]);
  }
  __syncthreads();
  for (int lr = sub; lr < 64; lr += 4)
    hT[(long)b * LL * CB + (long)(l0 + lr) * CB + c0 + ln] = t[ln][lr];
}

// ---------------------------------------------------------------------------
// 8-phase 256x256 GEMM (HK schedule, plain HIP): D = A[M][K] * Bt[N][K]^T.
// 8 waves (2M x 4N), per-wave 128x64 output (acc[8][4]); BK=64 K-tiles;
// 2 dbuf x {A,B} LDS regions (4 x 32 KB = 128 KB), XOR-swizzled staging
// (linear gload_lds dest + pre-swizzled source, rule #21).
// Schedule (derived race-free; region staged only after its death barrier):
//   iter i reads Ta=T(2i) [ph1-4, lA0/lB0], Tb=T(2i+1) [ph5-8, lA1/lB1].
//   stages: ph1,2 -> lA1 h0,h1 (T2i+1); ph3,4 -> lB0 (T2i+2);
//           ph5,6 -> lA0 (T2i+2); ph7,8 -> lB1 (T2i+3).
//   vmcnt(4) at ph4 & ph8 (2 VMEM/stage; leaves newest 2 stages in flight,
//   covers every region before first read); last iter: vmcnt(0) at ph4.
// EPI: 0 = QKV (by: 0,1=q 2,3=k -> [l][c] transposed; 4,5=v -> [c][l]; +bias)
//      1 = expS (bf16(exp2(acc*scale)))
// ---------------------------------------------------------------------------
template <int Q>
DI void rdA(const u16* LB, int wr, int fr, int fq, short8 af[2][2]) {
#pragma unroll
  for (int m2 = 0; m2 < 2; ++m2)
#pragma unroll
    for (int kk = 0; kk < 2; ++kk) {
      const int R = wr * 128 + (Q * 2 + m2) * 16 + fr;
      af[m2][kk] = *(const short8*)((const char*)LB + R * 128 +
                                    ((kk * 64 + fq * 16) ^ ((R & 7) << 4)));
    }
}
DI void rdB(const u16* LB, int wc, int fr, int fq, short8 bf[4][2]) {
#pragma unroll
  for (int nf = 0; nf < 4; ++nf)
#pragma unroll
    for (int kk = 0; kk < 2; ++kk) {
      const int R = wc * 64 + nf * 16 + fr;
      bf[nf][kk] = *(const short8*)((const char*)LB + R * 128 +
                                    ((kk * 64 + fq * 16) ^ ((R & 7) << 4)));
    }
}
template <int Q>
DI void mmaQ(short8 af[2][2], short8 bf[4][2], f32x4 acc[8][4]) {
#pragma unroll
  for (int kk = 0; kk < 2; ++kk)
#pragma unroll
    for (int m2 = 0; m2 < 2; ++m2)
#pragma unroll
      for (int nf = 0; nf < 4; ++nf)
        acc[Q * 2 + m2][nf] = __builtin_amdgcn_mfma_f32_16x16x32_bf16(
            af[m2][kk], bf[nf][kk], acc[Q * 2 + m2][nf], 0, 0, 0);
}

#define PTAIL(Q)                                             \
  __builtin_amdgcn_s_barrier();                              \
  asm volatile("s_waitcnt lgkmcnt(0)" ::: "memory");         \
  __builtin_amdgcn_sched_barrier(0);                         \
  __builtin_amdgcn_s_setprio(1);                             \
  mmaQ<Q>(af, bf, acc);                                      \
  __builtin_amdgcn_s_setprio(0);                             \
  __builtin_amdgcn_s_barrier();

template <int EPI>
__global__ __launch_bounds__(512, 2) void gemm8p(
    const u16* __restrict__ A, int lda, long asb,
    const u16* __restrict__ Bt, int ldb, long bsb,
    int K, const float* __restrict__ bias, float scale,
    u16* __restrict__ o0, u16* __restrict__ o1, u16* __restrict__ o2,
    long osb, int ldo) {
  __shared__ u16 smem[65536];                  // 128 KB
  u16* lA0 = smem;                             // [256][64] per region
  u16* lA1 = smem + 16384;
  u16* lB0 = smem + 32768;
  u16* lB1 = smem + 49152;

  const int tid = threadIdx.x;
  const int lane = tid & 63, wv = tid >> 6;
  const int wr = wv >> 2, wc = wv & 3;         // 2 x 4 waves
  const int fr = lane & 15, fq = lane >> 4;
  const int bx = blockIdx.x, by = blockIdx.y, bz = blockIdx.z;

  const u16* Ab = A + (long)bz * asb + (long)(by * 256) * lda;
  const u16* Bb = Bt + (long)bz * bsb + (long)(bx * 256) * ldb;

  // stage one half-tile (128 rows x 64 cols) = 2 gload_lds / thread
  auto stage = [&](u16* lbase, const u16* gbase, int ld_, int half, int t) {
#pragma unroll
    for (int p = 0; p < 2; ++p) {
      int i = p * 512 + tid;
      int row = i >> 3, ch = i & 7;
      int src = t * 64 + ((((ch << 4) ^ ((row & 7) << 4))) >> 1);
      gload16(gbase + (long)(half * 128 + row) * ld_ + src,
              lbase + half * 8192 + i * 8);
    }
  };

  f32x4 acc[8][4];
#pragma unroll
  for (int m = 0; m < 8; ++m)
#pragma unroll
    for (int n = 0; n < 4; ++n) acc[m][n] = (f32x4)(0.f);

  // prologue: A(T0), B(T0), B(T1); wait all but B(T1)'s 4 loads
  stage(lA0, Ab, lda, 0, 0); stage(lA0, Ab, lda, 1, 0);
  stage(lB0, Bb, ldb, 0, 0); stage(lB0, Bb, ldb, 1, 0);
  stage(lB1, Bb, ldb, 0, 1); stage(lB1, Bb, ldb, 1, 1);
  asm volatile("s_waitcnt vmcnt(4)" ::: "memory");
  __builtin_amdgcn_sched_barrier(0);
  __builtin_amdgcn_s_barrier();

  const int nt = K >> 6;                       // K-tiles (even, >= 4)
  short8 af[2][2], bf[4][2];
  for (int i = 0; i < nt / 2; ++i) {
    const bool last = (i == nt / 2 - 1);
    const int t1 = 2 * i + 1, t2 = 2 * i + 2, t3 = 2 * i + 3;
    // ---- Ta = T(2i) from lA0/lB0 ----
    rdB(lB0, wc, fr, fq, bf);
    rdA<0>(lA0, wr, fr, fq, af);
    stage(lA1, Ab, lda, 0, t1);
    PTAIL(0)
    rdA<1>(lA0, wr, fr, fq, af);
    stage(lA1, Ab, lda, 1, t1);
    PTAIL(1)
    rdA<2>(lA0, wr, fr, fq, af);
    if (!last) stage(lB0, Bb, ldb, 0, t2);
    PTAIL(2)
    rdA<3>(lA0, wr, fr, fq, af);
    if (!last) stage(lB0, Bb, ldb, 1, t2);
    if (last) { asm volatile("s_waitcnt vmcnt(0)" ::: "memory"); }
    else      { asm volatile("s_waitcnt vmcnt(4)" ::: "memory"); }
    __builtin_amdgcn_sched_barrier(0);
    PTAIL(3)
    // ---- Tb = T(2i+1) from lA1/lB1 ----
    rdB(lB1, wc, fr, fq, bf);
    rdA<0>(lA1, wr, fr, fq, af);
    if (!last) stage(lA0, Ab, lda, 0, t2);
    PTAIL(0)
    rdA<1>(lA1, wr, fr, fq, af);
    if (!last) stage(lA0, Ab, lda, 1, t2);
    PTAIL(1)
    rdA<2>(lA1, wr, fr, fq, af);
    if (!last) stage(lB1, Bb, ldb, 0, t3);
    PTAIL(2)
    rdA<3>(lA1, wr, fr, fq, af);
    if (!last) stage(lB1, Bb, ldb, 1, t3);
    if (!last) {
      asm volatile("s_waitcnt vmcnt(4)" ::: "memory");
      __builtin_amdgcn_sched_barrier(0);
    }
    PTAIL(3)
  }

  // ---- epilogue: repack 256x256 tile through smem, 16B stores ----
  if constexpr (EPI == 1) {
    // expS: bf16(exp2(acc*scale)), row-major [m][n]
#pragma unroll
    for (int mf = 0; mf < 8; ++mf)
#pragma unroll
      for (int nf = 0; nf < 4; ++nf) {
        const int nl = wc * 64 + nf * 16 + fr;
#pragma unroll
        for (int r = 0; r < 4; ++r) {
          const int ml = wr * 128 + mf * 16 + fq * 4 + r;
          smem[ml * 256 + (nl ^ ((ml & 7) << 3))] =
              f2bf(exp2f(acc[mf][nf][r] * scale));
        }
      }
    __syncthreads();
    u16* dst0 = o0 + (long)bz * osb + (long)(by * 256) * ldo + bx * 256;
    for (int i = tid * 8; i < 65536; i += 4096) {
      const int rr = i >> 8, cc = i & 255;
      short8 val = *(const short8*)&smem[rr * 256 + (cc ^ ((rr & 7) << 3))];
      *(short8*)(dst0 + (long)rr * ldo + cc) = val;
    }
  } else {
    // QKV: by 0,1 -> q; 2,3 -> k (transposed [l][c]); 4,5 -> v (natural [c][l])
    const int mat = by >> 1;
    if (mat < 2) {
      // transposed: smem row = l (nl), col = c (ml)
#pragma unroll
      for (int mf = 0; mf < 8; ++mf)
#pragma unroll
        for (int nf = 0; nf < 4; ++nf) {
          const int nl = wc * 64 + nf * 16 + fr;
#pragma unroll
          for (int r = 0; r < 4; ++r) {
            const int ml = wr * 128 + mf * 16 + fq * 4 + r;
            smem[nl * 256 + (ml ^ ((nl & 7) << 3))] =
                f2bf(acc[mf][nf][r] + bias[by * 256 + ml]);
          }
        }
      __syncthreads();
      u16* dst0 = (mat == 0 ? o0 : o1) + (long)bz * ((long)LL * CB) +
                  (long)(bx * 256) * CB + ((by * 256) & 511);
      for (int i = tid * 8; i < 65536; i += 4096) {
        const int rr = i >> 8, cc = i & 255;
        short8 val = *(const short8*)&smem[rr * 256 + (cc ^ ((rr & 7) << 3))];
        *(short8*)(dst0 + (long)rr * CB + cc) = val;
      }
    } else {
      // natural: smem row = c (ml), col = l (nl)
#pragma unroll
      for (int mf = 0; mf < 8; ++mf)
#pragma unroll
        for (int nf = 0; nf < 4; ++nf) {
          const int nl = wc * 64 + nf * 16 + fr;
#pragma unroll
          for (int r = 0; r < 4; ++r) {
            const int ml = wr * 128 + mf * 16 + fq * 4 + r;
            smem[ml * 256 + (nl ^ ((ml & 7) << 3))] =
                f2bf(acc[mf][nf][r] + bias[by * 256 + ml]);
          }
        }
      __syncthreads();
      u16* dst0 = o2 + (long)bz * ((long)CB * LL) +
                  (long)((by * 256) & 511) * LL + bx * 256;
      for (int i = tid * 8; i < 65536; i += 4096) {
        const int rr = i >> 8, cc = i & 255;
        short8 val = *(const short8*)&smem[rr * 256 + (cc ^ ((rr & 7) << 3))];
        *(short8*)(dst0 + (long)rr * LL + cc) = val;
      }
    }
  }
}

// ---------------------------------------------------------------------------
// m97-style GEMM skeleton (kept for PV split-K and fused out).
// EPI: 3=out (fp32 +bias +residual)
//      4=PV split-K normalized: bz=(g<<1)|chunk; bf16(acc*rls[row]) ->
//        (chunk? o1 : o0) + g*LL*CB; rls via xres.
// ---------------------------------------------------------------------------
template <int BM, int BN, int EPI, bool SWZ, int WR, int WC>
__global__ __launch_bounds__(WR * WC * 64) void gemm_bt(
    const u16* __restrict__ A, int lda, long asb,
    const u16* __restrict__ Bt, int ldb, long bsb,
    int K, const float* __restrict__ bias, float scale,
    u16* __restrict__ o0, u16* __restrict__ o1, u16* __restrict__ o2,
    float* __restrict__ of, const float* __restrict__ xres, long osb, int ldo) {
  constexpr int NT = WR * WC * 64;
  constexpr int FM = BM / WR / 16, FN = BN / WC / 16;
  static_assert((BM * 8) % NT == 0 && (BN * 8) % NT == 0, "staging div");
  __shared__ u16 smem[(BM + BN) * 64];
  u16* lA = smem;
  u16* lB = smem + BM * 64;

  int bx = blockIdx.x, by = blockIdx.y;
  if constexpr (SWZ) {
    const int nwg = gridDim.x * gridDim.y;
    const int id = by * gridDim.x + bx;
    const int id2 = (id & 7) * (nwg >> 3) + (id >> 3);
    bx = id2 % gridDim.x;
    by = id2 / gridDim.x;
  }

  const int tid = threadIdx.x;
  const int lane = tid & 63;
  const int wv = tid >> 6;
  const int wr = wv / WC, wc = wv % WC;
  const int fr = lane & 15, fq = lane >> 4;
  const int bz = blockIdx.z;
  const int bzb  = (EPI == 4) ? (bz >> 1) : bz;
  const int kbeg = (EPI == 4) ? (bz & 1) * K : 0;

  const u16* Ab = A + (long)bzb * asb + (long)(by * BM) * lda;
  const u16* Bb = Bt + (long)bzb * bsb + (long)(bx * BN) * ldb;

  f32x4 acc[FM][FN];
#pragma unroll
  for (int m = 0; m < FM; ++m)
#pragma unroll
    for (int n = 0; n < FN; ++n) acc[m][n] = (f32x4)(0.f);

  for (int k0 = kbeg; k0 < kbeg + K; k0 += 64) {
#pragma unroll
    for (int p = 0; p < BM * 8 / NT; ++p) {
      int t = p * NT + tid;
      int row = t >> 3;
      int cbl = ((t & 7) << 4) ^ ((row & 7) << 4);
      gload16(Ab + (long)row * lda + k0 + (cbl >> 1), &lA[t * 8]);
    }
#pragma unroll
    for (int p = 0; p < BN * 8 / NT; ++p) {
      int t = p * NT + tid;
      int row = t >> 3;
      int cbl = ((t & 7) << 4) ^ ((row & 7) << 4);
      gload16(Bb + (long)row * ldb + k0 + (cbl >> 1), &lB[t * 8]);
    }
    __syncthreads();
#pragma unroll
    for (int ks = 0; ks < 2; ++ks) {
      short8 af[FM], bfr[FN];
#pragma unroll
      for (int m = 0; m < FM; ++m) {
        int row = wr * (BM / WR) + m * 16 + fr;
        int cb = (ks * 64 + fq * 16) ^ ((row & 7) << 4);
        af[m] = *(const short8*)((const char*)lA + row * 128 + cb);
      }
#pragma unroll
      for (int n = 0; n < FN; ++n) {
        int row = wc * (BN / WC) + n * 16 + fr;
        int cb = (ks * 64 + fq * 16) ^ ((row & 7) << 4);
        bfr[n] = *(const short8*)((const char*)lB + row * 128 + cb);
      }
#pragma unroll
      for (int m = 0; m < FM; ++m)
#pragma unroll
        for (int n = 0; n < FN; ++n)
          acc[m][n] = __builtin_amdgcn_mfma_f32_16x16x32_bf16(af[m], bfr[n], acc[m][n], 0, 0, 0);
    }
    __syncthreads();
  }

  const int ml0 = wr * (BM / WR);
  const int nl0 = wc * (BN / WC);

  if constexpr (EPI == 3) {
    const int mg0 = by * BM + ml0;
    const int ng0 = bx * BN + nl0;
#pragma unroll
    for (int m = 0; m < FM; ++m)
#pragma unroll
      for (int n = 0; n < FN; ++n) {
        const int ng = ng0 + n * 16 + fr;
#pragma unroll
        for (int r = 0; r < 4; ++r) {
          const int mg = mg0 + m * 16 + fq * 4 + r;
          const long off = (long)bz * osb + (long)mg * ldo + ng;
          of[off] = acc[m][n][r] + bias[mg] + xres[off];
        }
      }
  } else {
    // EPI 4: split-K PV partial, normalized
    const float* rls = xres + (long)(bz >> 1) * LL + by * BM;
#pragma unroll
    for (int m = 0; m < FM; ++m)
#pragma unroll
      for (int n = 0; n < FN; ++n) {
        const int nl = nl0 + n * 16 + fr;
#pragma unroll
        for (int r = 0; r < 4; ++r) {
          const int ml = ml0 + m * 16 + fq * 4 + r;
          smem[ml * BN + (nl ^ ((ml & 7) << 3))] = f2bf(acc[m][n][r] * rls[ml]);
        }
      }
    __syncthreads();
    u16* dst0 = ((bz & 1) ? o1 : o0) + (long)(bz >> 1) * ((long)LL * CB) +
                (long)(by * BM) * ldo + bx * BN;
    for (int i = tid * 8; i < BM * BN; i += NT * 8) {
      const int rr = i / BN, cc = i % BN;
      short8 val = *(const short8*)&smem[rr * BN + (cc ^ ((rr & 7) << 3))];
      *(short8*)(dst0 + (long)rr * ldo + cc) = val;
    }
  }
}

// ---------------------------------------------------------------------------
// K4: rls[z][i] = 1 / sum_j expS[z][i][j].  One block per row; read-only pass.
// ---------------------------------------------------------------------------
__global__ __launch_bounds__(256) void rsum_rows(const u16* __restrict__ S,
                                                 float* __restrict__ rls) {
  const u16* row = S + ((long)blockIdx.y * LL + blockIdx.x) * LL;
  const int tid = threadIdx.x;
  const int wv = tid >> 6, ln = tid & 63;
  short8 a = ((const short8*)row)[tid * 2];
  short8 b = ((const short8*)row)[tid * 2 + 1];
  float s = 0.f;
#pragma unroll
  for (int j = 0; j < 8; ++j) s += bf2f((u16)a[j]) + bf2f((u16)b[j]);
#pragma unroll
  for (int o = 32; o; o >>= 1) s += __shfl_xor(s, o);
  __shared__ float red[4];
  if (ln == 0) red[wv] = s;
  __syncthreads();
  if (tid == 0)
    rls[(long)blockIdx.y * LL + blockIdx.x] =
        1.0f / (red[0] + red[1] + red[2] + red[3]);
}

// ---------------------------------------------------------------------------
// K5: sum two bf16 partial planes -> bf16 out plane.  grid (512, G).
// ---------------------------------------------------------------------------
__global__ __launch_bounds__(256) void reduce_pp(
    const u16* __restrict__ p0, const u16* __restrict__ p1, u16* __restrict__ o) {
  const long base = (long)blockIdx.y * ((long)LL * CB) +
                    (long)(blockIdx.x * 256 + threadIdx.x) * 16;
#pragma unroll
  for (int h = 0; h < 2; ++h) {
    short8 a = *(const short8*)(p0 + base + h * 8);
    short8 b = *(const short8*)(p1 + base + h * 8);
    short8 r;
#pragma unroll
    for (int j = 0; j < 8; ++j)
      r[j] = (short)f2bf(bf2f((u16)a[j]) + bf2f((u16)b[j]));
    *(short8*)(o + base + h * 8) = r;
  }
}

// ---------------------------------------------------------------------------
extern "C" void kernel_launch(void* const* d_in, const int* in_sizes, int n_in,
                              void* d_out, int out_size, void* d_ws, size_t ws_size,
                              hipStream_t stream) {
  const float* x   = (const float*)d_in[0];
  const float* gnw = (const float*)d_in[1];
  const float* gnb = (const float*)d_in[2];
  const float* wq  = (const float*)d_in[3];
  const float* bq  = (const float*)d_in[4];
  const float* wk  = (const float*)d_in[5];
  const float* bk  = (const float*)d_in[6];
  const float* wv  = (const float*)d_in[7];
  const float* bv  = (const float*)d_in[8];
  const float* wo  = (const float*)d_in[9];
  const float* bo  = (const float*)d_in[10];
  float* out = (float*)d_out;

  char* ws = (char*)d_ws;
  const long NEL = (long)LL * CB;          // 2M elems = 4 MB bf16 per batch-plane
  const long SEL = (long)LL * LL;          // 16M elems = 32 MB bf16 per batch S
  float* stats = (float*)ws;                               // 8 KB
  float* bqkv  = (float*)(ws + 8192);                      // 6 KB
  u16* wqkv = (u16*)(ws + 16384);                          // 1.5 MB
  u16* wob  = (u16*)(ws + 16384 + 1572864);                // 0.5 MB
  float* rlsm = (float*)(ws + (3l << 20));                 // G*16 KB
  u16* hT   = (u16*)(ws + (4l << 20));                     // 32 MB  [B][L][C]
  u16* qT   = hT + 8 * NEL;                                // 32 MB  [B][L][C]
  u16* kT   = qT + 8 * NEL;                                // 32 MB  [B][L][C]
  u16* vN   = kT + 8 * NEL;                                // 32 MB  [B][C][L]
  const size_t base = (4ul << 20) + 4ul * 8 * NEL * 2;     // 132 MB

  int G;
  u16 *Sbuf, *aT;
  if (ws_size >= base + 2ul * SEL * 2) G = 2;
  else                                 G = 1;
  if (G > 1) { Sbuf = (u16*)(ws + base); aT = hT; }        // hT dead after QKV
  else       { Sbuf = hT; aT = qT; }

  conv_w<<<1025, 256, 0, stream>>>(wq, wk, wv, wo, bq, bk, bv, wqkv, wob, bqkv);
  gn_stats<<<256, 256, 0, stream>>>(x, stats);
  gn_apply<<<dim3(64, 8, 8), 256, 0, stream>>>(x, gnw, gnb, stats, hT);

  // fused QKV, 8-phase 256^2: A=wqkv [1536][512], Bt=hT[b] [4096][512]
  gemm8p<0><<<dim3(16, 6, 8), 512, 0, stream>>>(
      wqkv, 512, 0, hT, 512, NEL, 512, bqkv, 1.f, qT, kT, vN, 0, 0);

  // no-max softmax (numerics proven r6/r7): expS = exp2(cl * q.k), rls = 1/rowsum
  const float cl = (1.0f / sqrtf(512.0f)) * 1.44269504f;
  for (int g0 = 0; g0 < 8; g0 += G) {
    // expS[z] = exp2(cl * qT[g0+z] * kT[g0+z]^T), 8-phase: M=N=4096, K=512
    gemm8p<1><<<dim3(16, 16, G), 512, 0, stream>>>(
        qT + (long)g0 * NEL, 512, NEL, kT + (long)g0 * NEL, 512, NEL, 512,
        nullptr, cl, Sbuf, nullptr, nullptr, SEL, LL);
    rsum_rows<<<dim3(LL, G), 256, 0, stream>>>(Sbuf, rlsm);
    // PV split-K, 8 waves/block, normalized partials -> dead qT/kT planes
    gemm_bt<128, 128, 4, true, 2, 4><<<dim3(4, 32, 2 * G), 512, 0, stream>>>(
        Sbuf, LL, SEL, vN + (long)g0 * NEL, LL, NEL, 2048,
        nullptr, 1.f, qT + (long)g0 * NEL, kT + (long)g0 * NEL, nullptr,
        nullptr, rlsm, 0, CB);
    reduce_pp<<<dim3(512, G), 256, 0, stream>>>(
        qT + (long)g0 * NEL, kT + (long)g0 * NEL, aT + (long)g0 * NEL);
  }

  // out = x + wo * attnT^T + bo : M=512, N=4096, K=512 per batch
  gemm_bt<128, 128, 3, false, 2, 2><<<dim3(32, 4, 8), 256, 0, stream>>>(
      wob, 512, 0, aT, 512, NEL, 512, bo, 1.f,
      nullptr, nullptr, nullptr, out, x, NEL, LL);

  (void)in_sizes; (void)n_in; (void)out_size; (void)ws_size;
}

// Round 11
// 597.540 us; speedup vs baseline: 1.3769x; 1.0358x over previous
//
#include <hip/hip_runtime.h>
#include <hip/hip_bf16.h>
#include <math.h>

#define DI __device__ __forceinline__

typedef unsigned short u16;
typedef unsigned int   u32;
typedef unsigned long long u64;
typedef __attribute__((ext_vector_type(8))) short short8;   // 8 bf16 (4 VGPRs) MFMA A/B frag
typedef __attribute__((ext_vector_type(4))) float f32x4;    // MFMA C/D frag

constexpr int CB = 512;    // channels
constexpr int LL = 4096;   // length
constexpr int NG = 32;     // groups
constexpr long NELC = (long)LL * CB;       // elems per [l][c] plane

DI float bf2f(u16 u) { u32 v = ((u32)u) << 16; float f; __builtin_memcpy(&f, &v, 4); return f; }
DI u16 f2bf(float f) {
  u32 u; __builtin_memcpy(&u, &f, 4);
  u += 0x7fffu + ((u >> 16) & 1u);   // RNE
  return (u16)(u >> 16);
}

DI void gload16(const void* g, void* l) {
  __builtin_amdgcn_global_load_lds((const __attribute__((address_space(1))) u32*)g,
                                   (__attribute__((address_space(3))) u32*)l, 16, 0, 0);
}

// ---------------------------------------------------------------------------
// K0: weights -> bf16 (wqkv fused [1536][512], wo [512][512]); fused bias.
// ---------------------------------------------------------------------------
__global__ __launch_bounds__(256) void conv_w(
    const float* __restrict__ wq, const float* __restrict__ wk,
    const float* __restrict__ wv, const float* __restrict__ wo,
    const float* __restrict__ bq, const float* __restrict__ bk,
    const float* __restrict__ bv,
    u16* __restrict__ wqkv, u16* __restrict__ wob, float* __restrict__ bqkv) {
  if (blockIdx.x < 1024) {
    int i = blockIdx.x * 256 + threadIdx.x;
    wqkv[i]          = f2bf(wq[i]);
    wqkv[262144 + i] = f2bf(wk[i]);
    wqkv[524288 + i] = f2bf(wv[i]);
    wob[i]           = f2bf(wo[i]);
  } else {
    for (int j = 0; j < 6; ++j) {
      int idx = j * 256 + threadIdx.x;
      float b = (idx < 512) ? bq[idx] : (idx < 1024) ? bk[idx - 512] : bv[idx - 1024];
      bqkv[idx] = b;
    }
  }
}

// ---------------------------------------------------------------------------
// K1: GroupNorm stats. One block per (b,g).
// ---------------------------------------------------------------------------
__global__ __launch_bounds__(256) void gn_stats(const float* __restrict__ x,
                                                float* __restrict__ stats) {
  const float4* base = (const float4*)(x + (long)blockIdx.x * (16 * LL));
  float s = 0.f, ss = 0.f;
  for (int i = threadIdx.x; i < 16 * LL / 4; i += 256) {
    float4 v = base[i];
    s  += v.x + v.y + v.z + v.w;
    ss += v.x * v.x + v.y * v.y + v.z * v.z + v.w * v.w;
  }
#pragma unroll
  for (int o = 32; o; o >>= 1) { s += __shfl_xor(s, o); ss += __shfl_xor(ss, o); }
  __shared__ float red[8];
  int wv = threadIdx.x >> 6, ln = threadIdx.x & 63;
  if (ln == 0) { red[wv * 2] = s; red[wv * 2 + 1] = ss; }
  __syncthreads();
  if (threadIdx.x == 0) {
    float S = red[0] + red[2] + red[4] + red[6];
    float SS = red[1] + red[3] + red[5] + red[7];
    float mu = S * (1.f / 65536.f);
    float var = SS * (1.f / 65536.f) - mu * mu;
    stats[blockIdx.x * 2]     = mu;
    stats[blockIdx.x * 2 + 1] = rsqrtf(var + 1e-6f);
  }
}

// ---------------------------------------------------------------------------
// K2: GroupNorm apply + transpose: hT[b][l][c] = bf16(gn(x[b][c][l]))
// ---------------------------------------------------------------------------
__global__ __launch_bounds__(256) void gn_apply(
    const float* __restrict__ x, const float* __restrict__ gw,
    const float* __restrict__ gb, const float* __restrict__ stats,
    u16* __restrict__ hT) {
  __shared__ u16 t[64][66];
  const int b = blockIdx.z, c0 = blockIdx.y * 64, l0 = blockIdx.x * 64;
  const int ln = threadIdx.x & 63, sub = threadIdx.x >> 6;
  for (int cr = sub; cr < 64; cr += 4) {
    int c = c0 + cr;
    float v  = x[(long)b * CB * LL + (long)c * LL + l0 + ln];
    float mu = stats[(b * NG + (c >> 4)) * 2];
    float rs = stats[(b * NG + (c >> 4)) * 2 + 1];
    t[cr][ln] = f2bf((v - mu) * rs * gw[c] + gb[c]);
  }
  __syncthreads();
  for (int lr = sub; lr < 64; lr += 4)
    hT[(long)b * LL * CB + (long)(l0 + lr) * CB + c0 + ln] = t[ln][lr];
}

// ---------------------------------------------------------------------------
// 8-phase 256x256 GEMM (HK schedule, plain HIP): D = A[M][K] * Bt[N][K]^T.
// 8 waves (2M x 4N), per-wave 128x64 output (acc[8][4]); BK=64 K-tiles;
// 2 dbuf x {A,B} LDS regions (4 x 32 KB = 128 KB), XOR-swizzled staging
// (linear gload_lds dest + pre-swizzled source, rule #21).
// Schedule (race-free; region staged only after its death barrier):
//   iter i reads Ta=T(2i) [ph1-4, lA0/lB0], Tb=T(2i+1) [ph5-8, lA1/lB1].
//   stages: ph1,2 -> lA1 (T2i+1); ph3,4 -> lB0 (T2i+2);
//           ph5,6 -> lA0 (T2i+2); ph7,8 -> lB1 (T2i+3).
//   vmcnt(4) at ph4 & ph8; last iter vmcnt(0) at ph4.
// EPI: 0 = QKV (by: 0,1=q 2,3=k -> [l][c] transposed; 4,5=v -> [c][l]; +bias)
//      1 = expS (bf16(exp2(acc*scale)))
//      2 = PV split-K partial: bz=(batch<<2)|chunk, K=chunk len; store
//          bf16(acc*rls[row]) into per-batch [4096][2048] chunk-interleaved
//          buffer at o0 + batch*4*NELC, col = chunk*512 + bx*256 + nl.
// ---------------------------------------------------------------------------
template <int Q>
DI void rdA(const u16* LB, int wr, int fr, int fq, short8 af[2][2]) {
#pragma unroll
  for (int m2 = 0; m2 < 2; ++m2)
#pragma unroll
    for (int kk = 0; kk < 2; ++kk) {
      const int R = wr * 128 + (Q * 2 + m2) * 16 + fr;
      af[m2][kk] = *(const short8*)((const char*)LB + R * 128 +
                                    ((kk * 64 + fq * 16) ^ ((R & 7) << 4)));
    }
}
DI void rdB(const u16* LB, int wc, int fr, int fq, short8 bf[4][2]) {
#pragma unroll
  for (int nf = 0; nf < 4; ++nf)
#pragma unroll
    for (int kk = 0; kk < 2; ++kk) {
      const int R = wc * 64 + nf * 16 + fr;
      bf[nf][kk] = *(const short8*)((const char*)LB + R * 128 +
                                    ((kk * 64 + fq * 16) ^ ((R & 7) << 4)));
    }
}
template <int Q>
DI void mmaQ(short8 af[2][2], short8 bf[4][2], f32x4 acc[8][4]) {
#pragma unroll
  for (int kk = 0; kk < 2; ++kk)
#pragma unroll
    for (int m2 = 0; m2 < 2; ++m2)
#pragma unroll
      for (int nf = 0; nf < 4; ++nf)
        acc[Q * 2 + m2][nf] = __builtin_amdgcn_mfma_f32_16x16x32_bf16(
            af[m2][kk], bf[nf][kk], acc[Q * 2 + m2][nf], 0, 0, 0);
}

#define PTAIL(Q)                                             \
  __builtin_amdgcn_s_barrier();                              \
  asm volatile("s_waitcnt lgkmcnt(0)" ::: "memory");         \
  __builtin_amdgcn_sched_barrier(0);                         \
  __builtin_amdgcn_s_setprio(1);                             \
  mmaQ<Q>(af, bf, acc);                                      \
  __builtin_amdgcn_s_setprio(0);                             \
  __builtin_amdgcn_s_barrier();

template <int EPI>
__global__ __launch_bounds__(512, 2) void gemm8p(
    const u16* __restrict__ A, int lda, long asb,
    const u16* __restrict__ Bt, int ldb, long bsb,
    int K, const float* __restrict__ bias, float scale,
    u16* __restrict__ o0, u16* __restrict__ o1, u16* __restrict__ o2,
    const float* __restrict__ rls, long osb, int ldo) {
  __shared__ u16 smem[65536];                  // 128 KB
  u16* lA0 = smem;                             // [256][64] per region
  u16* lA1 = smem + 16384;
  u16* lB0 = smem + 32768;
  u16* lB1 = smem + 49152;

  const int tid = threadIdx.x;
  const int lane = tid & 63, wv = tid >> 6;
  const int wr = wv >> 2, wc = wv & 3;         // 2 x 4 waves
  const int fr = lane & 15, fq = lane >> 4;
  const int bx = blockIdx.x, by = blockIdx.y, bz = blockIdx.z;
  const int bzb = (EPI == 2) ? (bz >> 2) : bz;       // batch
  const int tb  = (EPI == 2) ? (bz & 3) * (K >> 6) : 0;  // chunk tile base

  const u16* Ab = A + (long)bzb * asb + (long)(by * 256) * lda;
  const u16* Bb = Bt + (long)bzb * bsb + (long)(bx * 256) * ldb;

  // stage one half-tile (128 rows x 64 cols) = 2 gload_lds / thread
  auto stage = [&](u16* lbase, const u16* gbase, int ld_, int half, int t) {
#pragma unroll
    for (int p = 0; p < 2; ++p) {
      int i = p * 512 + tid;
      int row = i >> 3, ch = i & 7;
      int src = t * 64 + ((((ch << 4) ^ ((row & 7) << 4))) >> 1);
      gload16(gbase + (long)(half * 128 + row) * ld_ + src,
              lbase + half * 8192 + i * 8);
    }
  };

  f32x4 acc[8][4];
#pragma unroll
  for (int m = 0; m < 8; ++m)
#pragma unroll
    for (int n = 0; n < 4; ++n) acc[m][n] = (f32x4)(0.f);

  // prologue: A(T0), B(T0), B(T1); wait all but B(T1)'s 4 loads
  stage(lA0, Ab, lda, 0, tb); stage(lA0, Ab, lda, 1, tb);
  stage(lB0, Bb, ldb, 0, tb); stage(lB0, Bb, ldb, 1, tb);
  stage(lB1, Bb, ldb, 0, tb + 1); stage(lB1, Bb, ldb, 1, tb + 1);
  asm volatile("s_waitcnt vmcnt(4)" ::: "memory");
  __builtin_amdgcn_sched_barrier(0);
  __builtin_amdgcn_s_barrier();

  const int nt = K >> 6;                       // K-tiles (even, >= 4)
  short8 af[2][2], bf[4][2];
  for (int i = 0; i < nt / 2; ++i) {
    const bool last = (i == nt / 2 - 1);
    const int t1 = tb + 2 * i + 1, t2 = tb + 2 * i + 2, t3 = tb + 2 * i + 3;
    // ---- Ta = T(2i) from lA0/lB0 ----
    rdB(lB0, wc, fr, fq, bf);
    rdA<0>(lA0, wr, fr, fq, af);
    stage(lA1, Ab, lda, 0, t1);
    PTAIL(0)
    rdA<1>(lA0, wr, fr, fq, af);
    stage(lA1, Ab, lda, 1, t1);
    PTAIL(1)
    rdA<2>(lA0, wr, fr, fq, af);
    if (!last) stage(lB0, Bb, ldb, 0, t2);
    PTAIL(2)
    rdA<3>(lA0, wr, fr, fq, af);
    if (!last) stage(lB0, Bb, ldb, 1, t2);
    if (last) { asm volatile("s_waitcnt vmcnt(0)" ::: "memory"); }
    else      { asm volatile("s_waitcnt vmcnt(4)" ::: "memory"); }
    __builtin_amdgcn_sched_barrier(0);
    PTAIL(3)
    // ---- Tb = T(2i+1) from lA1/lB1 ----
    rdB(lB1, wc, fr, fq, bf);
    rdA<0>(lA1, wr, fr, fq, af);
    if (!last) stage(lA0, Ab, lda, 0, t2);
    PTAIL(0)
    rdA<1>(lA1, wr, fr, fq, af);
    if (!last) stage(lA0, Ab, lda, 1, t2);
    PTAIL(1)
    rdA<2>(lA1, wr, fr, fq, af);
    if (!last) stage(lB1, Bb, ldb, 0, t3);
    PTAIL(2)
    rdA<3>(lA1, wr, fr, fq, af);
    if (!last) stage(lB1, Bb, ldb, 1, t3);
    if (!last) {
      asm volatile("s_waitcnt vmcnt(4)" ::: "memory");
      __builtin_amdgcn_sched_barrier(0);
    }
    PTAIL(3)
  }

  // ---- epilogue: repack 256x256 tile through smem, 16B stores ----
  if constexpr (EPI == 1) {
    // expS: bf16(exp2(acc*scale)), row-major [m][n]
#pragma unroll
    for (int mf = 0; mf < 8; ++mf)
#pragma unroll
      for (int nf = 0; nf < 4; ++nf) {
        const int nl = wc * 64 + nf * 16 + fr;
#pragma unroll
        for (int r = 0; r < 4; ++r) {
          const int ml = wr * 128 + mf * 16 + fq * 4 + r;
          smem[ml * 256 + (nl ^ ((ml & 7) << 3))] =
              f2bf(exp2f(acc[mf][nf][r] * scale));
        }
      }
    __syncthreads();
    u16* dst0 = o0 + (long)bz * osb + (long)(by * 256) * ldo + bx * 256;
    for (int i = tid * 8; i < 65536; i += 4096) {
      const int rr = i >> 8, cc = i & 255;
      short8 val = *(const short8*)&smem[rr * 256 + (cc ^ ((rr & 7) << 3))];
      *(short8*)(dst0 + (long)rr * ldo + cc) = val;
    }
  } else if constexpr (EPI == 2) {
    // PV split-K partial, normalized: bf16(acc * rls[row]) -> [4096][2048]
    const float* rl = rls + (long)bzb * LL + by * 256;
#pragma unroll
    for (int mf = 0; mf < 8; ++mf)
#pragma unroll
      for (int nf = 0; nf < 4; ++nf) {
        const int nl = wc * 64 + nf * 16 + fr;
#pragma unroll
        for (int r = 0; r < 4; ++r) {
          const int ml = wr * 128 + mf * 16 + fq * 4 + r;
          smem[ml * 256 + (nl ^ ((ml & 7) << 3))] =
              f2bf(acc[mf][nf][r] * rl[ml]);
        }
      }
    __syncthreads();
    u16* dst0 = o0 + (long)bzb * 4 * NELC + (long)(by * 256) * 2048 +
                (bz & 3) * 512 + bx * 256;
    for (int i = tid * 8; i < 65536; i += 4096) {
      const int rr = i >> 8, cc = i & 255;
      short8 val = *(const short8*)&smem[rr * 256 + (cc ^ ((rr & 7) << 3))];
      *(short8*)(dst0 + (long)rr * 2048 + cc) = val;
    }
  } else {
    // QKV: by 0,1 -> q; 2,3 -> k (transposed [l][c]); 4,5 -> v (natural [c][l])
    const int mat = by >> 1;
    if (mat < 2) {
#pragma unroll
      for (int mf = 0; mf < 8; ++mf)
#pragma unroll
        for (int nf = 0; nf < 4; ++nf) {
          const int nl = wc * 64 + nf * 16 + fr;
#pragma unroll
          for (int r = 0; r < 4; ++r) {
            const int ml = wr * 128 + mf * 16 + fq * 4 + r;
            smem[nl * 256 + (ml ^ ((nl & 7) << 3))] =
                f2bf(acc[mf][nf][r] + bias[by * 256 + ml]);
          }
        }
      __syncthreads();
      u16* dst0 = (mat == 0 ? o0 : o1) + (long)bz * NELC +
                  (long)(bx * 256) * CB + ((by * 256) & 511);
      for (int i = tid * 8; i < 65536; i += 4096) {
        const int rr = i >> 8, cc = i & 255;
        short8 val = *(const short8*)&smem[rr * 256 + (cc ^ ((rr & 7) << 3))];
        *(short8*)(dst0 + (long)rr * CB + cc) = val;
      }
    } else {
#pragma unroll
      for (int mf = 0; mf < 8; ++mf)
#pragma unroll
        for (int nf = 0; nf < 4; ++nf) {
          const int nl = wc * 64 + nf * 16 + fr;
#pragma unroll
          for (int r = 0; r < 4; ++r) {
            const int ml = wr * 128 + mf * 16 + fq * 4 + r;
            smem[ml * 256 + (nl ^ ((ml & 7) << 3))] =
                f2bf(acc[mf][nf][r] + bias[by * 256 + ml]);
          }
        }
      __syncthreads();
      u16* dst0 = o2 + (long)bz * ((long)CB * LL) +
                  (long)((by * 256) & 511) * LL + bx * 256;
      for (int i = tid * 8; i < 65536; i += 4096) {
        const int rr = i >> 8, cc = i & 255;
        short8 val = *(const short8*)&smem[rr * 256 + (cc ^ ((rr & 7) << 3))];
        *(short8*)(dst0 + (long)rr * LL + cc) = val;
      }
    }
  }
}

// ---------------------------------------------------------------------------
// m97-style GEMM skeleton (out-projection; PV fallback for G=1).
// EPI: 3=out (fp32 +bias +residual)
//      4=PV split-K normalized (G=1 fallback): bz=(g<<1)|chunk;
//        bf16(acc*rls[row]) -> (chunk? o1 : o0) + g*NELC; rls via xres.
// ---------------------------------------------------------------------------
template <int BM, int BN, int EPI, bool SWZ, int WR, int WC>
__global__ __launch_bounds__(WR * WC * 64) void gemm_bt(
    const u16* __restrict__ A, int lda, long asb,
    const u16* __restrict__ Bt, int ldb, long bsb,
    int K, const float* __restrict__ bias, float scale,
    u16* __restrict__ o0, u16* __restrict__ o1, u16* __restrict__ o2,
    float* __restrict__ of, const float* __restrict__ xres, long osb, int ldo) {
  constexpr int NT = WR * WC * 64;
  constexpr int FM = BM / WR / 16, FN = BN / WC / 16;
  static_assert((BM * 8) % NT == 0 && (BN * 8) % NT == 0, "staging div");
  __shared__ u16 smem[(BM + BN) * 64];
  u16* lA = smem;
  u16* lB = smem + BM * 64;

  int bx = blockIdx.x, by = blockIdx.y;
  if constexpr (SWZ) {
    const int nwg = gridDim.x * gridDim.y;
    const int id = by * gridDim.x + bx;
    const int id2 = (id & 7) * (nwg >> 3) + (id >> 3);
    bx = id2 % gridDim.x;
    by = id2 / gridDim.x;
  }

  const int tid = threadIdx.x;
  const int lane = tid & 63;
  const int wv = tid >> 6;
  const int wr = wv / WC, wc = wv % WC;
  const int fr = lane & 15, fq = lane >> 4;
  const int bz = blockIdx.z;
  const int bzb  = (EPI == 4) ? (bz >> 1) : bz;
  const int kbeg = (EPI == 4) ? (bz & 1) * K : 0;

  const u16* Ab = A + (long)bzb * asb + (long)(by * BM) * lda;
  const u16* Bb = Bt + (long)bzb * bsb + (long)(bx * BN) * ldb;

  f32x4 acc[FM][FN];
#pragma unroll
  for (int m = 0; m < FM; ++m)
#pragma unroll
    for (int n = 0; n < FN; ++n) acc[m][n] = (f32x4)(0.f);

  for (int k0 = kbeg; k0 < kbeg + K; k0 += 64) {
#pragma unroll
    for (int p = 0; p < BM * 8 / NT; ++p) {
      int t = p * NT + tid;
      int row = t >> 3;
      int cbl = ((t & 7) << 4) ^ ((row & 7) << 4);
      gload16(Ab + (long)row * lda + k0 + (cbl >> 1), &lA[t * 8]);
    }
#pragma unroll
    for (int p = 0; p < BN * 8 / NT; ++p) {
      int t = p * NT + tid;
      int row = t >> 3;
      int cbl = ((t & 7) << 4) ^ ((row & 7) << 4);
      gload16(Bb + (long)row * ldb + k0 + (cbl >> 1), &lB[t * 8]);
    }
    __syncthreads();
#pragma unroll
    for (int ks = 0; ks < 2; ++ks) {
      short8 af[FM], bfr[FN];
#pragma unroll
      for (int m = 0; m < FM; ++m) {
        int row = wr * (BM / WR) + m * 16 + fr;
        int cb = (ks * 64 + fq * 16) ^ ((row & 7) << 4);
        af[m] = *(const short8*)((const char*)lA + row * 128 + cb);
      }
#pragma unroll
      for (int n = 0; n < FN; ++n) {
        int row = wc * (BN / WC) + n * 16 + fr;
        int cb = (ks * 64 + fq * 16) ^ ((row & 7) << 4);
        bfr[n] = *(const short8*)((const char*)lB + row * 128 + cb);
      }
#pragma unroll
      for (int m = 0; m < FM; ++m)
#pragma unroll
        for (int n = 0; n < FN; ++n)
          acc[m][n] = __builtin_amdgcn_mfma_f32_16x16x32_bf16(af[m], bfr[n], acc[m][n], 0, 0, 0);
    }
    __syncthreads();
  }

  const int ml0 = wr * (BM / WR);
  const int nl0 = wc * (BN / WC);

  if constexpr (EPI == 3) {
    const int mg0 = by * BM + ml0;
    const int ng0 = bx * BN + nl0;
#pragma unroll
    for (int m = 0; m < FM; ++m)
#pragma unroll
      for (int n = 0; n < FN; ++n) {
        const int ng = ng0 + n * 16 + fr;
#pragma unroll
        for (int r = 0; r < 4; ++r) {
          const int mg = mg0 + m * 16 + fq * 4 + r;
          const long off = (long)bz * osb + (long)mg * ldo + ng;
          of[off] = acc[m][n][r] + bias[mg] + xres[off];
        }
      }
  } else {
    // EPI 4: split-K PV partial, normalized (G=1 fallback)
    const float* rls = xres + (long)(bz >> 1) * LL + by * BM;
#pragma unroll
    for (int m = 0; m < FM; ++m)
#pragma unroll
      for (int n = 0; n < FN; ++n) {
        const int nl = nl0 + n * 16 + fr;
#pragma unroll
        for (int r = 0; r < 4; ++r) {
          const int ml = ml0 + m * 16 + fq * 4 + r;
          smem[ml * BN + (nl ^ ((ml & 7) << 3))] = f2bf(acc[m][n][r] * rls[ml]);
        }
      }
    __syncthreads();
    u16* dst0 = ((bz & 1) ? o1 : o0) + (long)(bz >> 1) * NELC +
                (long)(by * BM) * ldo + bx * BN;
    for (int i = tid * 8; i < BM * BN; i += NT * 8) {
      const int rr = i / BN, cc = i % BN;
      short8 val = *(const short8*)&smem[rr * BN + (cc ^ ((rr & 7) << 3))];
      *(short8*)(dst0 + (long)rr * ldo + cc) = val;
    }
  }
}

// ---------------------------------------------------------------------------
// K4: rls[z][i] = 1 / sum_j expS[z][i][j].  One block per row; read-only pass.
// ---------------------------------------------------------------------------
__global__ __launch_bounds__(256) void rsum_rows(const u16* __restrict__ S,
                                                 float* __restrict__ rls) {
  const u16* row = S + ((long)blockIdx.y * LL + blockIdx.x) * LL;
  const int tid = threadIdx.x;
  const int wv = tid >> 6, ln = tid & 63;
  short8 a = ((const short8*)row)[tid * 2];
  short8 b = ((const short8*)row)[tid * 2 + 1];
  float s = 0.f;
#pragma unroll
  for (int j = 0; j < 8; ++j) s += bf2f((u16)a[j]) + bf2f((u16)b[j]);
#pragma unroll
  for (int o = 32; o; o >>= 1) s += __shfl_xor(s, o);
  __shared__ float red[4];
  if (ln == 0) red[wv] = s;
  __syncthreads();
  if (tid == 0)
    rls[(long)blockIdx.y * LL + blockIdx.x] =
        1.0f / (red[0] + red[1] + red[2] + red[3]);
}

// ---------------------------------------------------------------------------
// K5: sum 4 interleaved chunk-partials [4096][2048] -> [4096][512] bf16.
//     grid (1024, 2): blockIdx.y = batch-local.
// ---------------------------------------------------------------------------
__global__ __launch_bounds__(256) void reduce4(
    const u16* __restrict__ P, u16* __restrict__ o) {
  const int b = blockIdx.y;
  const long idx = (long)blockIdx.x * 256 + threadIdx.x;   // 0..262143
  const int i = (int)(idx >> 6);                           // row 0..4095
  const int c0 = ((int)idx & 63) * 8;                      // channel
  const u16* Pb = P + (long)b * 4 * NELC + (long)i * 2048;
  float s[8] = {0.f, 0.f, 0.f, 0.f, 0.f, 0.f, 0.f, 0.f};
#pragma unroll
  for (int c4 = 0; c4 < 4; ++c4) {
    short8 v = *(const short8*)(Pb + c4 * 512 + c0);
#pragma unroll
    for (int j = 0; j < 8; ++j) s[j] += bf2f((u16)v[j]);
  }
  short8 r;
#pragma unroll
  for (int j = 0; j < 8; ++j) r[j] = (short)f2bf(s[j]);
  *(short8*)(o + (long)b * NELC + (long)i * 512 + c0) = r;
}

// ---------------------------------------------------------------------------
// K6 (G=1 fallback): sum two bf16 partial planes -> bf16 out plane.
// ---------------------------------------------------------------------------
__global__ __launch_bounds__(256) void reduce_pp(
    const u16* __restrict__ p0, const u16* __restrict__ p1, u16* __restrict__ o) {
  const long base = (long)blockIdx.y * NELC +
                    (long)(blockIdx.x * 256 + threadIdx.x) * 16;
#pragma unroll
  for (int h = 0; h < 2; ++h) {
    short8 a = *(const short8*)(p0 + base + h * 8);
    short8 b = *(const short8*)(p1 + base + h * 8);
    short8 r;
#pragma unroll
    for (int j = 0; j < 8; ++j)
      r[j] = (short)f2bf(bf2f((u16)a[j]) + bf2f((u16)b[j]));
    *(short8*)(o + base + h * 8) = r;
  }
}

// ---------------------------------------------------------------------------
extern "C" void kernel_launch(void* const* d_in, const int* in_sizes, int n_in,
                              void* d_out, int out_size, void* d_ws, size_t ws_size,
                              hipStream_t stream) {
  const float* x   = (const float*)d_in[0];
  const float* gnw = (const float*)d_in[1];
  const float* gnb = (const float*)d_in[2];
  const float* wq  = (const float*)d_in[3];
  const float* bq  = (const float*)d_in[4];
  const float* wk  = (const float*)d_in[5];
  const float* bk  = (const float*)d_in[6];
  const float* wv  = (const float*)d_in[7];
  const float* bv  = (const float*)d_in[8];
  const float* wo  = (const float*)d_in[9];
  const float* bo  = (const float*)d_in[10];
  float* out = (float*)d_out;

  char* ws = (char*)d_ws;
  const long NEL = NELC;                   // 2M elems = 4 MB bf16 per plane
  const long SEL = (long)LL * LL;          // 16M elems = 32 MB bf16 per batch S
  float* stats = (float*)ws;                               // 8 KB
  float* bqkv  = (float*)(ws + 8192);                      // 6 KB
  u16* wqkv = (u16*)(ws + 16384);                          // 1.5 MB
  u16* wob  = (u16*)(ws + 16384 + 1572864);                // 0.5 MB
  float* rlsm = (float*)(ws + (3l << 20));                 // G*16 KB
  u16* hT   = (u16*)(ws + (4l << 20));                     // 32 MB; PV partials after QKV
  u16* qT   = hT + 8 * NEL;                                // 32 MB  [B][L][C]
  u16* kT   = qT + 8 * NEL;                                // 32 MB  [B][L][C]
  u16* vN   = kT + 8 * NEL;                                // 32 MB  [B][C][L]
  const size_t base = (4ul << 20) + 4ul * 8 * NEL * 2;     // 132 MB

  const int G = (ws_size >= base + 2ul * SEL * 2) ? 2 : 1;
  u16* Sbuf = (G == 2) ? (u16*)(ws + base) : hT;

  conv_w<<<1025, 256, 0, stream>>>(wq, wk, wv, wo, bq, bk, bv, wqkv, wob, bqkv);
  gn_stats<<<256, 256, 0, stream>>>(x, stats);
  gn_apply<<<dim3(64, 8, 8), 256, 0, stream>>>(x, gnw, gnb, stats, hT);

  // fused QKV, 8-phase 256^2: A=wqkv [1536][512], Bt=hT[b] [4096][512]
  gemm8p<0><<<dim3(16, 6, 8), 512, 0, stream>>>(
      wqkv, 512, 0, hT, 512, NEL, 512, bqkv, 1.f, qT, kT, vN, nullptr, 0, 0);

  // no-max softmax (numerics proven r6/r7): expS = exp2(cl * q.k), rls = 1/rowsum
  const float cl = (1.0f / sqrtf(512.0f)) * 1.44269504f;
  for (int g0 = 0; g0 < 8; g0 += G) {
    // expS[z] = exp2(cl * qT[g0+z] * kT[g0+z]^T), 8-phase: M=N=4096, K=512
    gemm8p<1><<<dim3(16, 16, G), 512, 0, stream>>>(
        qT + (long)g0 * NEL, 512, NEL, kT + (long)g0 * NEL, 512, NEL, 512,
        nullptr, cl, Sbuf, nullptr, nullptr, nullptr, SEL, LL);
    rsum_rows<<<dim3(LL, G), 256, 0, stream>>>(Sbuf, rlsm);
    if (G == 2) {
      // PV 8-phase split-K=4: A=Sbuf [4096][4096], Bt=vN [512][4096];
      // partials (normalized) -> hT per-batch [4096][2048]; 256 blocks.
      gemm8p<2><<<dim3(2, 16, 8), 512, 0, stream>>>(
          Sbuf, LL, SEL, vN + (long)g0 * NEL, LL, NEL, 1024,
          nullptr, 1.f, hT, nullptr, nullptr, rlsm, 0, 0);
      // sum 4 chunks -> attn planes in dead qT pair slots
      reduce4<<<dim3(1024, 2), 256, 0, stream>>>(hT, qT + (long)g0 * NEL);
    } else {
      // fallback: m97 PV split-2 -> qT/kT planes, reduce in-place into qT
      gemm_bt<128, 128, 4, true, 2, 4><<<dim3(4, 32, 2), 512, 0, stream>>>(
          Sbuf, LL, SEL, vN + (long)g0 * NEL, LL, NEL, 2048,
          nullptr, 1.f, qT + (long)g0 * NEL, kT + (long)g0 * NEL, nullptr,
          nullptr, rlsm, 0, CB);
      reduce_pp<<<dim3(512, 1), 256, 0, stream>>>(
          qT + (long)g0 * NEL, kT + (long)g0 * NEL, qT + (long)g0 * NEL);
    }
  }

  // out = x + wo * attn^T + bo : attn planes live in qT; M=512, N=4096, K=512
  gemm_bt<128, 128, 3, false, 2, 2><<<dim3(32, 4, 8), 256, 0, stream>>>(
      wob, 512, 0, qT, 512, NEL, 512, bo, 1.f,
      nullptr, nullptr, nullptr, out, x, NEL, LL);

  (void)in_sizes; (void)n_in; (void)out_size; (void)ws_size;
}